// Round 6
// baseline (603.465 us; speedup 1.0000x reference)
//
#include <hip/hip_runtime.h>

#define D 128
#define BN_EPS 1e-5f
#define NSUB 1024
#define CAP2 2048

typedef __attribute__((ext_vector_type(8))) short short8;   // 8 x bf16 (4 VGPRs)
typedef __attribute__((ext_vector_type(4))) float floatx4;  // MFMA accumulator

__device__ __forceinline__ float bf2f(unsigned short u) {
    unsigned int x = ((unsigned int)u) << 16;
    return __builtin_bit_cast(float, x);
}
__device__ __forceinline__ unsigned short f2bf(float f) {
    unsigned int x = __builtin_bit_cast(unsigned int, f);
    x = x + 0x7FFFu + ((x >> 16) & 1u);  // round-to-nearest-even
    return (unsigned short)(x >> 16);
}
// exact floor(x / N) for x < 2^27 via host magic M = 2^44/N + 1 (N < 2^17)
__device__ __forceinline__ int magdiv(unsigned int x, unsigned long long magic) {
    return (int)(((unsigned long long)x * magic) >> 44);
}

// ---------------------------------------------------------------------------
// Merged setup: node_init + comb(fp32) + pack_w1 + pack_w2.
__global__ __launch_bounds__(256)
void setup_kernel(const int* __restrict__ x, const int* __restrict__ z,
                  const float* __restrict__ atom_emb, const float* __restrict__ z_emb,
                  unsigned short* __restrict__ hb, int N, int nbNode,
                  const float* __restrict__ bond_emb, float* __restrict__ comb,
                  const float* __restrict__ W1, unsigned short* __restrict__ w1p,
                  const float* __restrict__ W2, unsigned short* __restrict__ w2p) {
    const int b = blockIdx.x;
    const int tid = threadIdx.x;
    if (b < nbNode) {
        // ---- node_init: hb0 = bf16( sum_f atom_emb[f,x[n,f],:] + z_emb[z[n],:] )
        int gid = b * 256 + tid;
        int node = gid >> 5;
        if (node >= N) return;
        int d0 = (gid & 31) * 4;
        float4 acc = *(const float4*)(z_emb + (size_t)z[node] * D + d0);
#pragma unroll
        for (int f = 0; f < 9; ++f) {
            int v = x[node * 9 + f];
            const float4 t = *(const float4*)(atom_emb + (size_t)(f * 119 + v) * D + d0);
            acc.x += t.x; acc.y += t.y; acc.z += t.z; acc.w += t.w;
        }
        ushort4 o;
        o.x = f2bf(acc.x); o.y = f2bf(acc.y); o.z = f2bf(acc.z); o.w = f2bf(acc.w);
        *(ushort4*)(hb + (size_t)node * D + d0) = o;
    } else if (b < nbNode + 216) {
        // ---- comb[layer][c][d] = b0[a0][d]+b1[a1][d]+b2[a2][d]  (fp32, L2-resident)
        int t = (b - nbNode) * 256 + tid;
        int layer = t / (216 * D);
        int idx = t - layer * (216 * D);
        int c = idx >> 7, d = idx & 127;
        int a0 = c / 36, a1 = (c / 6) % 6, a2 = c % 6;
        const float* bb = bond_emb + (size_t)layer * 3 * 6 * D;
        float v = bb[(0 * 6 + a0) * D + d] + bb[(1 * 6 + a1) * D + d] + bb[(2 * 6 + a2) * D + d];
        comb[(size_t)layer * 216 * D + idx] = v;
    } else {
        // ---- pack W [K][NCOLS] fp32 row-major -> fragment-linear bf16
        int isW2 = (b >= nbNode + 216 + 256);
        int t = (b - nbNode - 216 - (isW2 ? 256 : 0)) * 256 + tid;
        int layer = t >> 15;           // total = 32768 per layer for both
        int idx = t & 32767;
        int logN = isW2 ? 7 : 8;
        int NCOLS = 1 << logN;
        int k = idx >> logN, n = idx & (NCOLS - 1);
        int k0 = k >> 5, kq = k & 31, q = kq >> 3, j = kq & 7;
        int tt = n >> 4, ln = n & 15;
        size_t dest = (((size_t)k0 * (NCOLS >> 4) + tt) << 9) + ((q << 4) + ln) * 8 + j;
        const float* W = (isW2 ? W2 : W1) + (size_t)layer * 32768;
        unsigned short* Wp = (isW2 ? w2p : w1p) + (size_t)layer * 32768;
        Wp[dest] = f2bf(W[idx]);
    }
}

// ---------------------------------------------------------------------------
// Single-pass 1024-way partition: edges -> 1024 sub-slice lists directly.
// Packed entry: src(17) | comb_idx<<17 (8) | local_dst<<25 (7).
__global__ __launch_bounds__(256)
void partition_kernel(const int* __restrict__ ei, const int* __restrict__ ea,
                      unsigned int* __restrict__ subL, int* __restrict__ tail2,
                      int E, int N, unsigned long long magic, int ntiles, int nblocks) {
    __shared__ int lcnt[1024], lbase[1024];
    const int tid = threadIdx.x;
    for (int tile = blockIdx.x; tile < ntiles; tile += nblocks) {
        const int tb = tile * 4096;
#pragma unroll
        for (int i = 0; i < 4; ++i) lcnt[tid + i * 256] = 0;
        __syncthreads();
        int sub[16];
        unsigned int entry[16];
#pragma unroll
        for (int j = 0; j < 16; ++j) {
            int e = tb + j * 256 + tid;
            if (e < E) {
                int dst = ei[E + e];
                int c = (ea[3 * e] * 6 + ea[3 * e + 1]) * 6 + ea[3 * e + 2];
                int k = magdiv((unsigned)dst * 1024u, magic);
                int lo = (int)(((long long)k * N + 1023) >> 10);
                sub[j] = k;
                entry[j] = (unsigned int)ei[e] | ((unsigned int)c << 17) |
                           ((unsigned int)(dst - lo) << 25);
                atomicAdd(&lcnt[k], 1);
            } else {
                sub[j] = -1;
            }
        }
        __syncthreads();
#pragma unroll
        for (int i = 0; i < 4; ++i) {
            int k = tid + i * 256;
            int c = lcnt[k];
            if (c) lbase[k] = atomicAdd(&tail2[k], c);
            lcnt[k] = 0;
        }
        __syncthreads();
#pragma unroll
        for (int j = 0; j < 16; ++j) {
            if (sub[j] >= 0) {
                int k = sub[j];
                int pos = lbase[k] + atomicAdd(&lcnt[k], 1);
                if (pos < CAP2) subL[(size_t)k * CAP2 + pos] = entry[j];
            }
        }
        __syncthreads();
    }
}

// ---------------------------------------------------------------------------
// Exclusive scan of 1024 sub-slice tails -> subbase; offsets[N] = E.
__global__ __launch_bounds__(1024)
void subscan_kernel(const int* __restrict__ tail2, int* __restrict__ subbase,
                    int* __restrict__ offsets, int N) {
    const int tid = threadIdx.x, lane = tid & 63, wid = tid >> 6;
    int v = min(tail2[tid], CAP2);
    int s = v;
#pragma unroll
    for (int off = 1; off < 64; off <<= 1) {
        int t = __shfl_up(s, off, 64);
        if (lane >= off) s += t;
    }
    __shared__ int ws[16];
    if (lane == 63) ws[wid] = s;
    __syncthreads();
    if (wid == 0) {
        int w = (lane < 16) ? ws[lane] : 0;
#pragma unroll
        for (int off = 1; off < 16; off <<= 1) {
            int t = __shfl_up(w, off, 64);
            if (lane >= off) w += t;
        }
        if (lane < 16) ws[lane] = w;
    }
    __syncthreads();
    int excl = (wid ? ws[wid - 1] : 0) + s - v;
    subbase[tid] = excl;
    if (tid == 1023) offsets[N] = excl + v;
}

// ---------------------------------------------------------------------------
// One block per sub-slice: LDS counting sort -> contiguous coalesced writes of
// bucket + offsets. No global scatter, no global cursor atomics.
__global__ __launch_bounds__(256)
void csr_sort_kernel(const unsigned int* __restrict__ subL, const int* __restrict__ tail2,
                     const int* __restrict__ subbase, int* __restrict__ offsets,
                     int* __restrict__ bucket, int N) {
    const int k = blockIdx.x;
    const int tid = threadIdx.x, lane = tid & 63, wid = tid >> 6;
    const int len = min(tail2[k], CAP2);
    const int base = subbase[k];
    const int lo = (int)(((long long)k * N + 1023) >> 10);
    const int hi = (int)(((long long)(k + 1) * N + 1023) >> 10);
    const int nn = hi - lo;  // <= 128
    __shared__ int cnt[128], loff[128], wsum[4];
    __shared__ unsigned int sorted[CAP2];
    const unsigned int* src = subL + (size_t)k * CAP2;

    if (tid < 128) cnt[tid] = 0;
    __syncthreads();
    for (int i = tid; i < len; i += 256) atomicAdd(&cnt[src[i] >> 25], 1);
    __syncthreads();
    // exclusive scan of cnt[0..127] (first 2 waves meaningful)
    int v = (tid < 128) ? cnt[tid] : 0;
    int s = v;
#pragma unroll
    for (int off = 1; off < 64; off <<= 1) {
        int t = __shfl_up(s, off, 64);
        if (lane >= off) s += t;
    }
    if (lane == 63) wsum[wid] = s;
    __syncthreads();
    if (tid < 128) loff[tid] = ((wid == 1) ? wsum[0] : 0) + s - v;
    __syncthreads();
    if (tid < nn) offsets[lo + tid] = base + loff[tid];
    if (tid < 128) cnt[tid] = 0;
    __syncthreads();
    for (int i = tid; i < len; i += 256) {
        unsigned int e = src[i];
        int ld = e >> 25;
        int pos = loff[ld] + atomicAdd(&cnt[ld], 1);
        sorted[pos] = e & 0x1FFFFFFu;
    }
    __syncthreads();
    for (int i = tid; i < len; i += 256) bucket[base + i] = (int)sorted[i];
}

// ---------------------------------------------------------------------------
// pre[n] = bf16( (1+eps)*h[n] + sum_{e in in(n)} relu(h[src_e] + comb[c_e]) )
// 16 threads/node, 4-edge unroll (8 loads in flight). comb fp32 (L2-hot).
// Measured pattern floor: ~68.5 us, FETCH 187 MB @ ~2.7 TB/s random-granule.
__global__ __launch_bounds__(256)
void gather_reduce_kernel(const int* __restrict__ offsets, const int* __restrict__ bucket,
                          const float* __restrict__ comb,
                          const unsigned short* __restrict__ hb,
                          const float* __restrict__ eps_l,
                          unsigned short* __restrict__ pre, int N) {
    int gid = blockIdx.x * blockDim.x + threadIdx.x;
    int node = gid >> 4;
    if (node >= N) return;
    int d0 = (gid & 15) * 8;

    union U8 { int4 i; unsigned short u[8]; };
    union C8 { float4 v[2]; float f[8]; };
    float s = 1.0f + eps_l[0];
    float a[8];
    {
        U8 hv; hv.i = *(const int4*)(hb + (size_t)node * D + d0);
#pragma unroll
        for (int j = 0; j < 8; ++j) a[j] = bf2f(hv.u[j]) * s;
    }
    const int beg = offsets[node], end = offsets[node + 1];
    for (int p = beg; p < end; p += 4) {
        int rem = end - p;
        int pk0 = bucket[p];
        int pk1 = bucket[rem > 1 ? p + 1 : p];
        int pk2 = bucket[rem > 2 ? p + 2 : p];
        int pk3 = bucket[rem > 3 ? p + 3 : p];
        U8 h0, h1, h2, h3;
        C8 c0, c1, c2, c3;
        h0.i = *(const int4*)(hb + (size_t)(pk0 & 0x1FFFF) * D + d0);
        c0.v[0] = *(const float4*)(comb + (size_t)(pk0 >> 17) * D + d0);
        c0.v[1] = *(const float4*)(comb + (size_t)(pk0 >> 17) * D + d0 + 4);
        h1.i = *(const int4*)(hb + (size_t)(pk1 & 0x1FFFF) * D + d0);
        c1.v[0] = *(const float4*)(comb + (size_t)(pk1 >> 17) * D + d0);
        c1.v[1] = *(const float4*)(comb + (size_t)(pk1 >> 17) * D + d0 + 4);
        h2.i = *(const int4*)(hb + (size_t)(pk2 & 0x1FFFF) * D + d0);
        c2.v[0] = *(const float4*)(comb + (size_t)(pk2 >> 17) * D + d0);
        c2.v[1] = *(const float4*)(comb + (size_t)(pk2 >> 17) * D + d0 + 4);
        h3.i = *(const int4*)(hb + (size_t)(pk3 & 0x1FFFF) * D + d0);
        c3.v[0] = *(const float4*)(comb + (size_t)(pk3 >> 17) * D + d0);
        c3.v[1] = *(const float4*)(comb + (size_t)(pk3 >> 17) * D + d0 + 4);
#pragma unroll
        for (int j = 0; j < 8; ++j) a[j] += fmaxf(bf2f(h0.u[j]) + c0.f[j], 0.0f);
        if (rem > 1) {
#pragma unroll
            for (int j = 0; j < 8; ++j) a[j] += fmaxf(bf2f(h1.u[j]) + c1.f[j], 0.0f);
        }
        if (rem > 2) {
#pragma unroll
            for (int j = 0; j < 8; ++j) a[j] += fmaxf(bf2f(h2.u[j]) + c2.f[j], 0.0f);
        }
        if (rem > 3) {
#pragma unroll
            for (int j = 0; j < 8; ++j) a[j] += fmaxf(bf2f(h3.u[j]) + c3.f[j], 0.0f);
        }
    }
    U8 o;
#pragma unroll
    for (int j = 0; j < 8; ++j) o.u[j] = f2bf(a[j]);
    *(int4*)(pre + (size_t)node * D + d0) = o.i;
}

// ---------------------------------------------------------------------------
// MFMA GEMM, B staged in LDS (2 x 32KB phases), A prefetched.
// Stats: block sums in LDS -> atomicAdd into global accumulator gacc[NCOLS*2]
// (no partial buffer, no strided reduce kernel).
template <int K, int NCOLS, int TRANSFORM, int OUTBF>
__global__ __launch_bounds__(256)
void mfma_gemm_kernel(const unsigned short* __restrict__ A,
                      const unsigned short* __restrict__ Wp,
                      const float* __restrict__ bias,
                      const float* __restrict__ tscale, const float* __restrict__ tshift,
                      unsigned short* __restrict__ Cbf, float* __restrict__ Cf,
                      float* __restrict__ gacc, int M) {
    constexpr int NT = NCOLS / 16;
    constexpr int NCHUNK = K / 32;
    constexpr int CPP = NCHUNK / 2;
    __shared__ unsigned short Ws[16384];
    __shared__ float red[NCOLS * 2];

    const int tid = threadIdx.x;
    const int wave = tid >> 6, lane = tid & 63;
    const int quad = lane >> 4, ln = lane & 15;
    const int m_base = blockIdx.x * 64 + wave * 16;
    int arow = m_base + ln;
    if (arow >= M) arow = M - 1;
    const int kq = quad * 8;

    int4 araw[NCHUNK];
#pragma unroll
    for (int c = 0; c < NCHUNK; ++c)
        araw[c] = *(const int4*)(A + (size_t)arow * K + c * 32 + kq);

    for (int i = tid; i < NCOLS * 2; i += 256) red[i] = 0.f;

    floatx4 acc[NT];
#pragma unroll
    for (int t = 0; t < NT; ++t) acc[t] = (floatx4){0.f, 0.f, 0.f, 0.f};

#pragma unroll
    for (int ph = 0; ph < 2; ++ph) {
        if (ph) __syncthreads();
#pragma unroll
        for (int i = 0; i < 16384; i += 2048)
            *(int4*)&Ws[i + tid * 8] = *(const int4*)&Wp[ph * 16384 + i + tid * 8];
        __syncthreads();
#pragma unroll
        for (int cc = 0; cc < CPP; ++cc) {
            const int c = ph * CPP + cc;
            short8 afrag;
            if constexpr (TRANSFORM) {
                union { int4 i; unsigned short u[8]; } raw;
                raw.i = araw[c];
                const int kb = c * 32 + kq;
                float4 sc0 = *(const float4*)(tscale + kb);
                float4 sc1 = *(const float4*)(tscale + kb + 4);
                float4 sh0 = *(const float4*)(tshift + kb);
                float4 sh1 = *(const float4*)(tshift + kb + 4);
                union { short8 v; unsigned short u[8]; } au;
                au.u[0] = f2bf(fmaxf(bf2f(raw.u[0]) * sc0.x + sh0.x, 0.f));
                au.u[1] = f2bf(fmaxf(bf2f(raw.u[1]) * sc0.y + sh0.y, 0.f));
                au.u[2] = f2bf(fmaxf(bf2f(raw.u[2]) * sc0.z + sh0.z, 0.f));
                au.u[3] = f2bf(fmaxf(bf2f(raw.u[3]) * sc0.w + sh0.w, 0.f));
                au.u[4] = f2bf(fmaxf(bf2f(raw.u[4]) * sc1.x + sh1.x, 0.f));
                au.u[5] = f2bf(fmaxf(bf2f(raw.u[5]) * sc1.y + sh1.y, 0.f));
                au.u[6] = f2bf(fmaxf(bf2f(raw.u[6]) * sc1.z + sh1.z, 0.f));
                au.u[7] = f2bf(fmaxf(bf2f(raw.u[7]) * sc1.w + sh1.w, 0.f));
                afrag = au.v;
            } else {
                afrag = __builtin_bit_cast(short8, araw[c]);
            }
#pragma unroll
            for (int t = 0; t < NT; ++t) {
                short8 bfrag = *(const short8*)&Ws[(((cc * NT) + t) << 9) + lane * 8];
                acc[t] = __builtin_amdgcn_mfma_f32_16x16x32_bf16(afrag, bfrag, acc[t], 0, 0, 0);
            }
        }
    }

#pragma unroll
    for (int t = 0; t < NT; ++t) {
        int col = t * 16 + ln;
        float bv = bias[col];
        float sv = 0.f, qv = 0.f;
#pragma unroll
        for (int r = 0; r < 4; ++r) {
            int row = m_base + quad * 4 + r;
            if (row < M) {
                float v = acc[t][r] + bv;
                sv += v; qv += v * v;
                if constexpr (OUTBF) Cbf[(size_t)row * NCOLS + col] = f2bf(v);
                else                 Cf[(size_t)row * NCOLS + col] = v;
            }
        }
        sv += __shfl_xor(sv, 16, 64); sv += __shfl_xor(sv, 32, 64);
        qv += __shfl_xor(qv, 16, 64); qv += __shfl_xor(qv, 32, 64);
        if (quad == 0) {
            atomicAdd(&red[col], sv);
            atomicAdd(&red[NCOLS + col], qv);
        }
    }
    __syncthreads();
    for (int i = tid; i < NCOLS * 2; i += 256) atomicAdd(&gacc[i], red[i]);
}

// ---------------------------------------------------------------------------
// One tiny block: gacc -> scale/shift, then re-zero gacc for next use.
template <int NCOLS>
__global__ void stats_final_kernel(float* __restrict__ gacc,
                                   const float* __restrict__ g, const float* __restrict__ b,
                                   float* __restrict__ scale, float* __restrict__ shift,
                                   float invN) {
    int col = threadIdx.x;
    if (col < NCOLS) {
        float s = gacc[col], q = gacc[NCOLS + col];
        float mean = s * invN;
        float var = q * invN - mean * mean;
        float inv = 1.0f / sqrtf(var + BN_EPS);
        float sc = g[col] * inv;
        scale[col] = sc;
        shift[col] = b[col] - mean * sc;
        gacc[col] = 0.f;
        gacc[NCOLS + col] = 0.f;
    }
}

// ---------------------------------------------------------------------------
// Reads bf16 raw out2. mode 0: hb = bf16(relu(bn(x))); mode 1: h = bn(x) fp32.
__global__ void bn_apply_kernel(const unsigned short* __restrict__ Xb,
                                float* __restrict__ Yf, unsigned short* __restrict__ Yb,
                                const float* __restrict__ scale, const float* __restrict__ shift,
                                int N, int mode) {
    int gid = blockIdx.x * blockDim.x + threadIdx.x;
    int node = gid >> 5;
    if (node >= N) return;
    int d0 = (gid & 31) * 4;
    ushort4 b = *(const ushort4*)(Xb + (size_t)node * D + d0);
    float4 v;
    v.x = bf2f(b.x); v.y = bf2f(b.y); v.z = bf2f(b.z); v.w = bf2f(b.w);
    float4 sc = *(const float4*)(scale + d0);
    float4 sh = *(const float4*)(shift + d0);
    float4 o;
    o.x = v.x * sc.x + sh.x;
    o.y = v.y * sc.y + sh.y;
    o.z = v.z * sc.z + sh.z;
    o.w = v.w * sc.w + sh.w;
    if (mode == 0) {
        ushort4 ob;
        ob.x = f2bf(fmaxf(o.x, 0.f));
        ob.y = f2bf(fmaxf(o.y, 0.f));
        ob.z = f2bf(fmaxf(o.z, 0.f));
        ob.w = f2bf(fmaxf(o.w, 0.f));
        *(ushort4*)(Yb + (size_t)node * D + d0) = ob;
    } else {
        *(float4*)(Yf + (size_t)node * D + d0) = o;
    }
}

// ---------------------------------------------------------------------------
extern "C" void kernel_launch(void* const* d_in, const int* in_sizes, int n_in,
                              void* d_out, int out_size, void* d_ws, size_t ws_size,
                              hipStream_t stream) {
    const int*   x        = (const int*)d_in[0];
    const int*   z        = (const int*)d_in[1];
    const int*   ei       = (const int*)d_in[2];
    const int*   ea       = (const int*)d_in[3];
    const float* atom_emb = (const float*)d_in[4];
    const float* z_emb    = (const float*)d_in[5];
    const float* bond_emb = (const float*)d_in[6];
    const float* eps      = (const float*)d_in[7];
    const float* W1       = (const float*)d_in[8];
    const float* b1       = (const float*)d_in[9];
    const float* g1       = (const float*)d_in[10];
    const float* be1      = (const float*)d_in[11];
    const float* W2       = (const float*)d_in[12];
    const float* b2       = (const float*)d_in[13];
    const float* bng      = (const float*)d_in[14];
    const float* bnb      = (const float*)d_in[15];

    const int N = in_sizes[1];
    const int E = in_sizes[3] / 3;

    float* h = (float*)d_out;  // final [N,128] fp32

    const int ngb = (N + 63) / 64;   // GEMM grid
    const unsigned long long magic = ((1ULL << 44) / (unsigned int)N) + 1;  // exact for x < 2^27

    char* ws = (char*)d_ws;
    size_t off = 0;
    auto alloc = [&](size_t bytes) { void* p = ws + off; off += (bytes + 255) & ~(size_t)255; return p; };
    unsigned short* pre_bf = (unsigned short*)alloc((size_t)N * D * 2);      // 25.6 MB
    unsigned short* out2_bf = pre_bf;            // gemm2 raw output (pre is dead by then)
    unsigned short* out1_bf = (unsigned short*)alloc((size_t)N * 2 * D * 2); // 51.2 MB
    unsigned short* hb      = (unsigned short*)alloc((size_t)N * D * 2);     // 25.6 MB
    int* offsets = (int*)alloc((size_t)(N + 1) * 4);
    int* bucket  = (int*)alloc((size_t)E * 4);
    unsigned int* subL = (unsigned int*)alloc((size_t)NSUB * CAP2 * 4); // 8 MB
    int* subbase = (int*)alloc(NSUB * 4);
    float* stats = (float*)alloc(1024 * 4);      // scale/shift outputs
    float* gstats = (float*)alloc(1024 * 4);     // global stats accumulators
    unsigned short* w1p  = (unsigned short*)alloc((size_t)2 * D * 2 * D * 2);
    unsigned short* w2p  = (unsigned short*)alloc((size_t)2 * 2 * D * D * 2);
    float* comb = (float*)alloc((size_t)2 * 216 * D * 4);    // fp32 comb, 221 KB
    // transient tail2 aliases out1_bf (dead until first GEMM1 write)
    int* tail2 = (int*)out1_bf;   // 1024 ints

    float* scale1 = stats;          // 256
    float* shift1 = stats + 256;    // 256
    float* scale2 = stats + 512;    // 128
    float* shift2 = stats + 640;    // 128
    float* gacc1 = gstats;          // 512 (sum 256 + sumsq 256)
    float* gacc2 = gstats + 512;    // 256 (sum 128 + sumsq 128)

    const float invN = 1.0f / (float)N;
    const int ntiles = (E + 4095) / 4096;
    const int nbNode = (N * 32 + 255) / 256;

    // --- CSR build: single-pass 1024-way partition -> subscan -> LDS sort ---
    hipMemsetAsync(tail2, 0, NSUB * sizeof(int), stream);
    hipMemsetAsync(gstats, 0, 1024 * sizeof(float), stream);
    partition_kernel<<<256, 256, 0, stream>>>(ei, ea, subL, tail2, E, N, magic, ntiles, 256);
    subscan_kernel<<<1, 1024, 0, stream>>>(tail2, subbase, offsets, N);
    csr_sort_kernel<<<NSUB, 256, 0, stream>>>(subL, tail2, subbase, offsets, bucket, N);

    // --- merged setup: node_init + comb + pack_w1 + pack_w2 ---
    setup_kernel<<<nbNode + 216 + 256 + 256, 256, 0, stream>>>(
        x, z, atom_emb, z_emb, hb, N, nbNode, bond_emb, comb, W1, w1p, W2, w2p);

    for (int l = 0; l < 2; ++l) {
        gather_reduce_kernel<<<(N * 16 + 255) / 256, 256, 0, stream>>>(
            offsets, bucket, comb + (size_t)l * 216 * D, hb, eps + l, pre_bf, N);

        mfma_gemm_kernel<128, 256, 0, 1><<<ngb, 256, 0, stream>>>(
            pre_bf, w1p + (size_t)l * D * 2 * D, b1 + (size_t)l * 2 * D,
            nullptr, nullptr, out1_bf, nullptr, gacc1, N);
        stats_final_kernel<256><<<1, 256, 0, stream>>>(
            gacc1, g1 + (size_t)l * 2 * D, be1 + (size_t)l * 2 * D, scale1, shift1, invN);

        // raw out2 in bf16 for both layers (stats computed from fp32 acc pre-round)
        mfma_gemm_kernel<256, 128, 1, 1><<<ngb, 256, 0, stream>>>(
            out1_bf, w2p + (size_t)l * 2 * D * D, b2 + (size_t)l * D,
            scale1, shift1, out2_bf, nullptr, gacc2, N);
        stats_final_kernel<128><<<1, 128, 0, stream>>>(
            gacc2, bng + (size_t)l * D, bnb + (size_t)l * D, scale2, shift2, invN);

        bn_apply_kernel<<<(N * 32 + 255) / 256, 256, 0, stream>>>(
            out2_bf, h, hb, scale2, shift2, N, l == 0 ? 0 : 1);
    }
}

// Round 7
// 525.499 us; speedup vs baseline: 1.1484x; 1.1484x over previous
//
#include <hip/hip_runtime.h>

#define D 128
#define BN_EPS 1e-5f
#define NSUB 1024
#define CAP2 2048
#define NCOPY 64   // stats accumulator copies (kills same-address atomic chains)

typedef __attribute__((ext_vector_type(8))) short short8;   // 8 x bf16 (4 VGPRs)
typedef __attribute__((ext_vector_type(4))) float floatx4;  // MFMA accumulator

__device__ __forceinline__ float bf2f(unsigned short u) {
    unsigned int x = ((unsigned int)u) << 16;
    return __builtin_bit_cast(float, x);
}
__device__ __forceinline__ unsigned short f2bf(float f) {
    unsigned int x = __builtin_bit_cast(unsigned int, f);
    x = x + 0x7FFFu + ((x >> 16) & 1u);  // round-to-nearest-even
    return (unsigned short)(x >> 16);
}
// exact floor(x / N) for x < 2^27 via host magic M = 2^44/N + 1 (N < 2^17)
__device__ __forceinline__ int magdiv(unsigned int x, unsigned long long magic) {
    return (int)(((unsigned long long)x * magic) >> 44);
}

// ---------------------------------------------------------------------------
// Merged setup: node_init + comb(fp32) + pack_w1 + pack_w2.
__global__ __launch_bounds__(256)
void setup_kernel(const int* __restrict__ x, const int* __restrict__ z,
                  const float* __restrict__ atom_emb, const float* __restrict__ z_emb,
                  unsigned short* __restrict__ hb, int N, int nbNode,
                  const float* __restrict__ bond_emb, float* __restrict__ comb,
                  const float* __restrict__ W1, unsigned short* __restrict__ w1p,
                  const float* __restrict__ W2, unsigned short* __restrict__ w2p) {
    const int b = blockIdx.x;
    const int tid = threadIdx.x;
    if (b < nbNode) {
        // ---- node_init: hb0 = bf16( sum_f atom_emb[f,x[n,f],:] + z_emb[z[n],:] )
        int gid = b * 256 + tid;
        int node = gid >> 5;
        if (node >= N) return;
        int d0 = (gid & 31) * 4;
        float4 acc = *(const float4*)(z_emb + (size_t)z[node] * D + d0);
#pragma unroll
        for (int f = 0; f < 9; ++f) {
            int v = x[node * 9 + f];
            const float4 t = *(const float4*)(atom_emb + (size_t)(f * 119 + v) * D + d0);
            acc.x += t.x; acc.y += t.y; acc.z += t.z; acc.w += t.w;
        }
        ushort4 o;
        o.x = f2bf(acc.x); o.y = f2bf(acc.y); o.z = f2bf(acc.z); o.w = f2bf(acc.w);
        *(ushort4*)(hb + (size_t)node * D + d0) = o;
    } else if (b < nbNode + 216) {
        // ---- comb[layer][c][d] = b0[a0][d]+b1[a1][d]+b2[a2][d]  (fp32, L2-resident)
        int t = (b - nbNode) * 256 + tid;
        int layer = t / (216 * D);
        int idx = t - layer * (216 * D);
        int c = idx >> 7, d = idx & 127;
        int a0 = c / 36, a1 = (c / 6) % 6, a2 = c % 6;
        const float* bb = bond_emb + (size_t)layer * 3 * 6 * D;
        float v = bb[(0 * 6 + a0) * D + d] + bb[(1 * 6 + a1) * D + d] + bb[(2 * 6 + a2) * D + d];
        comb[(size_t)layer * 216 * D + idx] = v;
    } else {
        // ---- pack W [K][NCOLS] fp32 row-major -> fragment-linear bf16
        int isW2 = (b >= nbNode + 216 + 256);
        int t = (b - nbNode - 216 - (isW2 ? 256 : 0)) * 256 + tid;
        int layer = t >> 15;           // total = 32768 per layer for both
        int idx = t & 32767;
        int logN = isW2 ? 7 : 8;
        int NCOLS = 1 << logN;
        int k = idx >> logN, n = idx & (NCOLS - 1);
        int k0 = k >> 5, kq = k & 31, q = kq >> 3, j = kq & 7;
        int tt = n >> 4, ln = n & 15;
        size_t dest = (((size_t)k0 * (NCOLS >> 4) + tt) << 9) + ((q << 4) + ln) * 8 + j;
        const float* W = (isW2 ? W2 : W1) + (size_t)layer * 32768;
        unsigned short* Wp = (isW2 ? w2p : w1p) + (size_t)layer * 32768;
        Wp[dest] = f2bf(W[idx]);
    }
}

// ---------------------------------------------------------------------------
// Single-pass 1024-way partition: edges -> 1024 sub-slice lists directly.
// Packed entry: src(17) | comb_idx<<17 (8) | local_dst<<25 (7).
__global__ __launch_bounds__(256)
void partition_kernel(const int* __restrict__ ei, const int* __restrict__ ea,
                      unsigned int* __restrict__ subL, int* __restrict__ tail2,
                      int E, int N, unsigned long long magic, int ntiles, int nblocks) {
    __shared__ int lcnt[1024], lbase[1024];
    const int tid = threadIdx.x;
    for (int tile = blockIdx.x; tile < ntiles; tile += nblocks) {
        const int tb = tile * 4096;
#pragma unroll
        for (int i = 0; i < 4; ++i) lcnt[tid + i * 256] = 0;
        __syncthreads();
        int sub[16];
        unsigned int entry[16];
#pragma unroll
        for (int j = 0; j < 16; ++j) {
            int e = tb + j * 256 + tid;
            if (e < E) {
                int dst = ei[E + e];
                int c = (ea[3 * e] * 6 + ea[3 * e + 1]) * 6 + ea[3 * e + 2];
                int k = magdiv((unsigned)dst * 1024u, magic);
                int lo = (int)(((long long)k * N + 1023) >> 10);
                sub[j] = k;
                entry[j] = (unsigned int)ei[e] | ((unsigned int)c << 17) |
                           ((unsigned int)(dst - lo) << 25);
                atomicAdd(&lcnt[k], 1);
            } else {
                sub[j] = -1;
            }
        }
        __syncthreads();
#pragma unroll
        for (int i = 0; i < 4; ++i) {
            int k = tid + i * 256;
            int c = lcnt[k];
            if (c) lbase[k] = atomicAdd(&tail2[k], c);
            lcnt[k] = 0;
        }
        __syncthreads();
#pragma unroll
        for (int j = 0; j < 16; ++j) {
            if (sub[j] >= 0) {
                int k = sub[j];
                int pos = lbase[k] + atomicAdd(&lcnt[k], 1);
                if (pos < CAP2) subL[(size_t)k * CAP2 + pos] = entry[j];
            }
        }
        __syncthreads();
    }
}

// ---------------------------------------------------------------------------
// Exclusive scan of 1024 sub-slice tails -> subbase; offsets[N] = E.
__global__ __launch_bounds__(1024)
void subscan_kernel(const int* __restrict__ tail2, int* __restrict__ subbase,
                    int* __restrict__ offsets, int N) {
    const int tid = threadIdx.x, lane = tid & 63, wid = tid >> 6;
    int v = min(tail2[tid], CAP2);
    int s = v;
#pragma unroll
    for (int off = 1; off < 64; off <<= 1) {
        int t = __shfl_up(s, off, 64);
        if (lane >= off) s += t;
    }
    __shared__ int ws[16];
    if (lane == 63) ws[wid] = s;
    __syncthreads();
    if (wid == 0) {
        int w = (lane < 16) ? ws[lane] : 0;
#pragma unroll
        for (int off = 1; off < 16; off <<= 1) {
            int t = __shfl_up(w, off, 64);
            if (lane >= off) w += t;
        }
        if (lane < 16) ws[lane] = w;
    }
    __syncthreads();
    int excl = (wid ? ws[wid - 1] : 0) + s - v;
    subbase[tid] = excl;
    if (tid == 1023) offsets[N] = excl + v;
}

// ---------------------------------------------------------------------------
// One block per sub-slice: LDS counting sort -> contiguous coalesced writes of
// bucket + offsets. No global scatter, no global cursor atomics.
__global__ __launch_bounds__(256)
void csr_sort_kernel(const unsigned int* __restrict__ subL, const int* __restrict__ tail2,
                     const int* __restrict__ subbase, int* __restrict__ offsets,
                     int* __restrict__ bucket, int N) {
    const int k = blockIdx.x;
    const int tid = threadIdx.x, lane = tid & 63, wid = tid >> 6;
    const int len = min(tail2[k], CAP2);
    const int base = subbase[k];
    const int lo = (int)(((long long)k * N + 1023) >> 10);
    const int hi = (int)(((long long)(k + 1) * N + 1023) >> 10);
    const int nn = hi - lo;  // <= 128
    __shared__ int cnt[128], loff[128], wsum[4];
    __shared__ unsigned int sorted[CAP2];
    const unsigned int* src = subL + (size_t)k * CAP2;

    if (tid < 128) cnt[tid] = 0;
    __syncthreads();
    for (int i = tid; i < len; i += 256) atomicAdd(&cnt[src[i] >> 25], 1);
    __syncthreads();
    // exclusive scan of cnt[0..127] (first 2 waves meaningful)
    int v = (tid < 128) ? cnt[tid] : 0;
    int s = v;
#pragma unroll
    for (int off = 1; off < 64; off <<= 1) {
        int t = __shfl_up(s, off, 64);
        if (lane >= off) s += t;
    }
    if (lane == 63) wsum[wid] = s;
    __syncthreads();
    if (tid < 128) loff[tid] = ((wid == 1) ? wsum[0] : 0) + s - v;
    __syncthreads();
    if (tid < nn) offsets[lo + tid] = base + loff[tid];
    if (tid < 128) cnt[tid] = 0;
    __syncthreads();
    for (int i = tid; i < len; i += 256) {
        unsigned int e = src[i];
        int ld = e >> 25;
        int pos = loff[ld] + atomicAdd(&cnt[ld], 1);
        sorted[pos] = e & 0x1FFFFFFu;
    }
    __syncthreads();
    for (int i = tid; i < len; i += 256) bucket[base + i] = (int)sorted[i];
}

// ---------------------------------------------------------------------------
// pre[n] = bf16( (1+eps)*h[n] + sum_{e in in(n)} relu(h[src_e] + comb[c_e]) )
// 16 threads/node, 4-edge unroll (8 loads in flight). comb fp32 (L2-hot).
// Measured pattern floor: ~68.5 us, FETCH 187 MB @ ~2.7 TB/s random-granule.
__global__ __launch_bounds__(256)
void gather_reduce_kernel(const int* __restrict__ offsets, const int* __restrict__ bucket,
                          const float* __restrict__ comb,
                          const unsigned short* __restrict__ hb,
                          const float* __restrict__ eps_l,
                          unsigned short* __restrict__ pre, int N) {
    int gid = blockIdx.x * blockDim.x + threadIdx.x;
    int node = gid >> 4;
    if (node >= N) return;
    int d0 = (gid & 15) * 8;

    union U8 { int4 i; unsigned short u[8]; };
    union C8 { float4 v[2]; float f[8]; };
    float s = 1.0f + eps_l[0];
    float a[8];
    {
        U8 hv; hv.i = *(const int4*)(hb + (size_t)node * D + d0);
#pragma unroll
        for (int j = 0; j < 8; ++j) a[j] = bf2f(hv.u[j]) * s;
    }
    const int beg = offsets[node], end = offsets[node + 1];
    for (int p = beg; p < end; p += 4) {
        int rem = end - p;
        int pk0 = bucket[p];
        int pk1 = bucket[rem > 1 ? p + 1 : p];
        int pk2 = bucket[rem > 2 ? p + 2 : p];
        int pk3 = bucket[rem > 3 ? p + 3 : p];
        U8 h0, h1, h2, h3;
        C8 c0, c1, c2, c3;
        h0.i = *(const int4*)(hb + (size_t)(pk0 & 0x1FFFF) * D + d0);
        c0.v[0] = *(const float4*)(comb + (size_t)(pk0 >> 17) * D + d0);
        c0.v[1] = *(const float4*)(comb + (size_t)(pk0 >> 17) * D + d0 + 4);
        h1.i = *(const int4*)(hb + (size_t)(pk1 & 0x1FFFF) * D + d0);
        c1.v[0] = *(const float4*)(comb + (size_t)(pk1 >> 17) * D + d0);
        c1.v[1] = *(const float4*)(comb + (size_t)(pk1 >> 17) * D + d0 + 4);
        h2.i = *(const int4*)(hb + (size_t)(pk2 & 0x1FFFF) * D + d0);
        c2.v[0] = *(const float4*)(comb + (size_t)(pk2 >> 17) * D + d0);
        c2.v[1] = *(const float4*)(comb + (size_t)(pk2 >> 17) * D + d0 + 4);
        h3.i = *(const int4*)(hb + (size_t)(pk3 & 0x1FFFF) * D + d0);
        c3.v[0] = *(const float4*)(comb + (size_t)(pk3 >> 17) * D + d0);
        c3.v[1] = *(const float4*)(comb + (size_t)(pk3 >> 17) * D + d0 + 4);
#pragma unroll
        for (int j = 0; j < 8; ++j) a[j] += fmaxf(bf2f(h0.u[j]) + c0.f[j], 0.0f);
        if (rem > 1) {
#pragma unroll
            for (int j = 0; j < 8; ++j) a[j] += fmaxf(bf2f(h1.u[j]) + c1.f[j], 0.0f);
        }
        if (rem > 2) {
#pragma unroll
            for (int j = 0; j < 8; ++j) a[j] += fmaxf(bf2f(h2.u[j]) + c2.f[j], 0.0f);
        }
        if (rem > 3) {
#pragma unroll
            for (int j = 0; j < 8; ++j) a[j] += fmaxf(bf2f(h3.u[j]) + c3.f[j], 0.0f);
        }
    }
    U8 o;
#pragma unroll
    for (int j = 0; j < 8; ++j) o.u[j] = f2bf(a[j]);
    *(int4*)(pre + (size_t)node * D + d0) = o.i;
}

// ---------------------------------------------------------------------------
// MFMA GEMM, B staged in LDS (2 x 32KB phases), A prefetched.
// Stats: block sums in LDS -> atomicAdd into gacc copy (blockIdx & 63).
// 64 copies cap same-address atomic chains at ~25 (R6 lesson: 1563-deep
// chains on 512 addresses serialized the whole kernel to 89 us).
template <int K, int NCOLS, int TRANSFORM, int OUTBF>
__global__ __launch_bounds__(256)
void mfma_gemm_kernel(const unsigned short* __restrict__ A,
                      const unsigned short* __restrict__ Wp,
                      const float* __restrict__ bias,
                      const float* __restrict__ tscale, const float* __restrict__ tshift,
                      unsigned short* __restrict__ Cbf, float* __restrict__ Cf,
                      float* __restrict__ gacc, int M) {
    constexpr int NT = NCOLS / 16;
    constexpr int NCHUNK = K / 32;
    constexpr int CPP = NCHUNK / 2;
    __shared__ unsigned short Ws[16384];
    __shared__ float red[NCOLS * 2];

    const int tid = threadIdx.x;
    const int wave = tid >> 6, lane = tid & 63;
    const int quad = lane >> 4, ln = lane & 15;
    const int m_base = blockIdx.x * 64 + wave * 16;
    int arow = m_base + ln;
    if (arow >= M) arow = M - 1;
    const int kq = quad * 8;

    int4 araw[NCHUNK];
#pragma unroll
    for (int c = 0; c < NCHUNK; ++c)
        araw[c] = *(const int4*)(A + (size_t)arow * K + c * 32 + kq);

    for (int i = tid; i < NCOLS * 2; i += 256) red[i] = 0.f;

    floatx4 acc[NT];
#pragma unroll
    for (int t = 0; t < NT; ++t) acc[t] = (floatx4){0.f, 0.f, 0.f, 0.f};

#pragma unroll
    for (int ph = 0; ph < 2; ++ph) {
        if (ph) __syncthreads();
#pragma unroll
        for (int i = 0; i < 16384; i += 2048)
            *(int4*)&Ws[i + tid * 8] = *(const int4*)&Wp[ph * 16384 + i + tid * 8];
        __syncthreads();
#pragma unroll
        for (int cc = 0; cc < CPP; ++cc) {
            const int c = ph * CPP + cc;
            short8 afrag;
            if constexpr (TRANSFORM) {
                union { int4 i; unsigned short u[8]; } raw;
                raw.i = araw[c];
                const int kb = c * 32 + kq;
                float4 sc0 = *(const float4*)(tscale + kb);
                float4 sc1 = *(const float4*)(tscale + kb + 4);
                float4 sh0 = *(const float4*)(tshift + kb);
                float4 sh1 = *(const float4*)(tshift + kb + 4);
                union { short8 v; unsigned short u[8]; } au;
                au.u[0] = f2bf(fmaxf(bf2f(raw.u[0]) * sc0.x + sh0.x, 0.f));
                au.u[1] = f2bf(fmaxf(bf2f(raw.u[1]) * sc0.y + sh0.y, 0.f));
                au.u[2] = f2bf(fmaxf(bf2f(raw.u[2]) * sc0.z + sh0.z, 0.f));
                au.u[3] = f2bf(fmaxf(bf2f(raw.u[3]) * sc0.w + sh0.w, 0.f));
                au.u[4] = f2bf(fmaxf(bf2f(raw.u[4]) * sc1.x + sh1.x, 0.f));
                au.u[5] = f2bf(fmaxf(bf2f(raw.u[5]) * sc1.y + sh1.y, 0.f));
                au.u[6] = f2bf(fmaxf(bf2f(raw.u[6]) * sc1.z + sh1.z, 0.f));
                au.u[7] = f2bf(fmaxf(bf2f(raw.u[7]) * sc1.w + sh1.w, 0.f));
                afrag = au.v;
            } else {
                afrag = __builtin_bit_cast(short8, araw[c]);
            }
#pragma unroll
            for (int t = 0; t < NT; ++t) {
                short8 bfrag = *(const short8*)&Ws[(((cc * NT) + t) << 9) + lane * 8];
                acc[t] = __builtin_amdgcn_mfma_f32_16x16x32_bf16(afrag, bfrag, acc[t], 0, 0, 0);
            }
        }
    }

#pragma unroll
    for (int t = 0; t < NT; ++t) {
        int col = t * 16 + ln;
        float bv = bias[col];
        float sv = 0.f, qv = 0.f;
#pragma unroll
        for (int r = 0; r < 4; ++r) {
            int row = m_base + quad * 4 + r;
            if (row < M) {
                float v = acc[t][r] + bv;
                sv += v; qv += v * v;
                if constexpr (OUTBF) Cbf[(size_t)row * NCOLS + col] = f2bf(v);
                else                 Cf[(size_t)row * NCOLS + col] = v;
            }
        }
        sv += __shfl_xor(sv, 16, 64); sv += __shfl_xor(sv, 32, 64);
        qv += __shfl_xor(qv, 16, 64); qv += __shfl_xor(qv, 32, 64);
        if (quad == 0) {
            atomicAdd(&red[col], sv);
            atomicAdd(&red[NCOLS + col], qv);
        }
    }
    __syncthreads();
    float* gout = gacc + (size_t)(blockIdx.x & (NCOPY - 1)) * (NCOLS * 2);
    for (int i = tid; i < NCOLS * 2; i += 256) atomicAdd(&gout[i], red[i]);
}

// ---------------------------------------------------------------------------
// One block: reduce 64 gacc copies -> scale/shift; re-zero copies for reuse.
template <int NCOLS>
__global__ void stats_final_kernel(float* __restrict__ gacc,
                                   const float* __restrict__ g, const float* __restrict__ b,
                                   float* __restrict__ scale, float* __restrict__ shift,
                                   float invN) {
    int col = threadIdx.x;
    if (col < NCOLS) {
        float s = 0.f, q = 0.f;
        for (int c = 0; c < NCOPY; ++c) {
            float* p = gacc + (size_t)c * (NCOLS * 2);
            s += p[col];
            q += p[NCOLS + col];
            p[col] = 0.f;
            p[NCOLS + col] = 0.f;
        }
        float mean = s * invN;
        float var = q * invN - mean * mean;
        float inv = 1.0f / sqrtf(var + BN_EPS);
        float sc = g[col] * inv;
        scale[col] = sc;
        shift[col] = b[col] - mean * sc;
    }
}

// ---------------------------------------------------------------------------
// Reads bf16 raw out2. mode 0: hb = bf16(relu(bn(x))); mode 1: h = bn(x) fp32.
__global__ void bn_apply_kernel(const unsigned short* __restrict__ Xb,
                                float* __restrict__ Yf, unsigned short* __restrict__ Yb,
                                const float* __restrict__ scale, const float* __restrict__ shift,
                                int N, int mode) {
    int gid = blockIdx.x * blockDim.x + threadIdx.x;
    int node = gid >> 5;
    if (node >= N) return;
    int d0 = (gid & 31) * 4;
    ushort4 b = *(const ushort4*)(Xb + (size_t)node * D + d0);
    float4 v;
    v.x = bf2f(b.x); v.y = bf2f(b.y); v.z = bf2f(b.z); v.w = bf2f(b.w);
    float4 sc = *(const float4*)(scale + d0);
    float4 sh = *(const float4*)(shift + d0);
    float4 o;
    o.x = v.x * sc.x + sh.x;
    o.y = v.y * sc.y + sh.y;
    o.z = v.z * sc.z + sh.z;
    o.w = v.w * sc.w + sh.w;
    if (mode == 0) {
        ushort4 ob;
        ob.x = f2bf(fmaxf(o.x, 0.f));
        ob.y = f2bf(fmaxf(o.y, 0.f));
        ob.z = f2bf(fmaxf(o.z, 0.f));
        ob.w = f2bf(fmaxf(o.w, 0.f));
        *(ushort4*)(Yb + (size_t)node * D + d0) = ob;
    } else {
        *(float4*)(Yf + (size_t)node * D + d0) = o;
    }
}

// ---------------------------------------------------------------------------
extern "C" void kernel_launch(void* const* d_in, const int* in_sizes, int n_in,
                              void* d_out, int out_size, void* d_ws, size_t ws_size,
                              hipStream_t stream) {
    const int*   x        = (const int*)d_in[0];
    const int*   z        = (const int*)d_in[1];
    const int*   ei       = (const int*)d_in[2];
    const int*   ea       = (const int*)d_in[3];
    const float* atom_emb = (const float*)d_in[4];
    const float* z_emb    = (const float*)d_in[5];
    const float* bond_emb = (const float*)d_in[6];
    const float* eps      = (const float*)d_in[7];
    const float* W1       = (const float*)d_in[8];
    const float* b1       = (const float*)d_in[9];
    const float* g1       = (const float*)d_in[10];
    const float* be1      = (const float*)d_in[11];
    const float* W2       = (const float*)d_in[12];
    const float* b2       = (const float*)d_in[13];
    const float* bng      = (const float*)d_in[14];
    const float* bnb      = (const float*)d_in[15];

    const int N = in_sizes[1];
    const int E = in_sizes[3] / 3;

    float* h = (float*)d_out;  // final [N,128] fp32

    const int ngb = (N + 63) / 64;   // GEMM grid
    const unsigned long long magic = ((1ULL << 44) / (unsigned int)N) + 1;  // exact for x < 2^27

    char* ws = (char*)d_ws;
    size_t off = 0;
    auto alloc = [&](size_t bytes) { void* p = ws + off; off += (bytes + 255) & ~(size_t)255; return p; };
    unsigned short* pre_bf = (unsigned short*)alloc((size_t)N * D * 2);      // 25.6 MB
    unsigned short* out2_bf = pre_bf;            // gemm2 raw output (pre is dead by then)
    unsigned short* out1_bf = (unsigned short*)alloc((size_t)N * 2 * D * 2); // 51.2 MB
    unsigned short* hb      = (unsigned short*)alloc((size_t)N * D * 2);     // 25.6 MB
    int* offsets = (int*)alloc((size_t)(N + 1) * 4);
    int* bucket  = (int*)alloc((size_t)E * 4);
    unsigned int* subL = (unsigned int*)alloc((size_t)NSUB * CAP2 * 4); // 8 MB
    int* subbase = (int*)alloc(NSUB * 4);
    float* stats = (float*)alloc(1024 * 4);                       // scale/shift outputs
    float* gstats = (float*)alloc((size_t)NCOPY * 768 * 4);       // 64 copies x (512+256)
    unsigned short* w1p  = (unsigned short*)alloc((size_t)2 * D * 2 * D * 2);
    unsigned short* w2p  = (unsigned short*)alloc((size_t)2 * 2 * D * D * 2);
    float* comb = (float*)alloc((size_t)2 * 216 * D * 4);    // fp32 comb, 221 KB
    // transient tail2 aliases out1_bf (dead until first GEMM1 write)
    int* tail2 = (int*)out1_bf;   // 1024 ints

    float* scale1 = stats;          // 256
    float* shift1 = stats + 256;    // 256
    float* scale2 = stats + 512;    // 128
    float* shift2 = stats + 640;    // 128
    float* gacc1 = gstats;                          // NCOPY x 512
    float* gacc2 = gstats + (size_t)NCOPY * 512;    // NCOPY x 256

    const float invN = 1.0f / (float)N;
    const int ntiles = (E + 4095) / 4096;
    const int nbNode = (N * 32 + 255) / 256;

    // --- CSR build: single-pass 1024-way partition -> subscan -> LDS sort ---
    hipMemsetAsync(tail2, 0, NSUB * sizeof(int), stream);
    hipMemsetAsync(gstats, 0, (size_t)NCOPY * 768 * sizeof(float), stream);
    partition_kernel<<<256, 256, 0, stream>>>(ei, ea, subL, tail2, E, N, magic, ntiles, 256);
    subscan_kernel<<<1, 1024, 0, stream>>>(tail2, subbase, offsets, N);
    csr_sort_kernel<<<NSUB, 256, 0, stream>>>(subL, tail2, subbase, offsets, bucket, N);

    // --- merged setup: node_init + comb + pack_w1 + pack_w2 ---
    setup_kernel<<<nbNode + 216 + 256 + 256, 256, 0, stream>>>(
        x, z, atom_emb, z_emb, hb, N, nbNode, bond_emb, comb, W1, w1p, W2, w2p);

    for (int l = 0; l < 2; ++l) {
        gather_reduce_kernel<<<(N * 16 + 255) / 256, 256, 0, stream>>>(
            offsets, bucket, comb + (size_t)l * 216 * D, hb, eps + l, pre_bf, N);

        mfma_gemm_kernel<128, 256, 0, 1><<<ngb, 256, 0, stream>>>(
            pre_bf, w1p + (size_t)l * D * 2 * D, b1 + (size_t)l * 2 * D,
            nullptr, nullptr, out1_bf, nullptr, gacc1, N);
        stats_final_kernel<256><<<1, 256, 0, stream>>>(
            gacc1, g1 + (size_t)l * 2 * D, be1 + (size_t)l * 2 * D, scale1, shift1, invN);

        // raw out2 in bf16 for both layers (stats computed from fp32 acc pre-round)
        mfma_gemm_kernel<256, 128, 1, 1><<<ngb, 256, 0, stream>>>(
            out1_bf, w2p + (size_t)l * 2 * D * D, b2 + (size_t)l * D,
            scale1, shift1, out2_bf, nullptr, gacc2, N);
        stats_final_kernel<128><<<1, 128, 0, stream>>>(
            gacc2, bng + (size_t)l * D, bnb + (size_t)l * D, scale2, shift2, invN);

        bn_apply_kernel<<<(N * 32 + 255) / 256, 256, 0, stream>>>(
            out2_bf, h, hb, scale2, shift2, N, l == 0 ? 0 : 1);
    }
}

// Round 8
// 502.713 us; speedup vs baseline: 1.2004x; 1.0453x over previous
//
#include <hip/hip_runtime.h>

#define D 128
#define BN_EPS 1e-5f
#define NSUB 1024
#define CAP2 2048
#define NCOPY 64   // stats accumulator copies (kills same-address atomic chains)

typedef __attribute__((ext_vector_type(8))) short short8;   // 8 x bf16 (4 VGPRs)
typedef __attribute__((ext_vector_type(4))) float floatx4;  // MFMA accumulator

__device__ __forceinline__ float bf2f(unsigned short u) {
    unsigned int x = ((unsigned int)u) << 16;
    return __builtin_bit_cast(float, x);
}
__device__ __forceinline__ unsigned short f2bf(float f) {
    unsigned int x = __builtin_bit_cast(unsigned int, f);
    x = x + 0x7FFFu + ((x >> 16) & 1u);  // round-to-nearest-even
    return (unsigned short)(x >> 16);
}
// exact floor(x / N) for x < 2^27 via host magic M = 2^44/N + 1 (N < 2^17)
__device__ __forceinline__ int magdiv(unsigned int x, unsigned long long magic) {
    return (int)(((unsigned long long)x * magic) >> 44);
}

// ---------------------------------------------------------------------------
// Merged setup: node_init + comb(fp32) + pack_w1 + pack_w2.
__global__ __launch_bounds__(256)
void setup_kernel(const int* __restrict__ x, const int* __restrict__ z,
                  const float* __restrict__ atom_emb, const float* __restrict__ z_emb,
                  unsigned short* __restrict__ hb, int N, int nbNode,
                  const float* __restrict__ bond_emb, float* __restrict__ comb,
                  const float* __restrict__ W1, unsigned short* __restrict__ w1p,
                  const float* __restrict__ W2, unsigned short* __restrict__ w2p) {
    const int b = blockIdx.x;
    const int tid = threadIdx.x;
    if (b < nbNode) {
        // ---- node_init: hb0 = bf16( sum_f atom_emb[f,x[n,f],:] + z_emb[z[n],:] )
        int gid = b * 256 + tid;
        int node = gid >> 5;
        if (node >= N) return;
        int d0 = (gid & 31) * 4;
        float4 acc = *(const float4*)(z_emb + (size_t)z[node] * D + d0);
#pragma unroll
        for (int f = 0; f < 9; ++f) {
            int v = x[node * 9 + f];
            const float4 t = *(const float4*)(atom_emb + (size_t)(f * 119 + v) * D + d0);
            acc.x += t.x; acc.y += t.y; acc.z += t.z; acc.w += t.w;
        }
        ushort4 o;
        o.x = f2bf(acc.x); o.y = f2bf(acc.y); o.z = f2bf(acc.z); o.w = f2bf(acc.w);
        *(ushort4*)(hb + (size_t)node * D + d0) = o;
    } else if (b < nbNode + 216) {
        // ---- comb[layer][c][d] = b0[a0][d]+b1[a1][d]+b2[a2][d]  (fp32, L2-resident)
        int t = (b - nbNode) * 256 + tid;
        int layer = t / (216 * D);
        int idx = t - layer * (216 * D);
        int c = idx >> 7, d = idx & 127;
        int a0 = c / 36, a1 = (c / 6) % 6, a2 = c % 6;
        const float* bb = bond_emb + (size_t)layer * 3 * 6 * D;
        float v = bb[(0 * 6 + a0) * D + d] + bb[(1 * 6 + a1) * D + d] + bb[(2 * 6 + a2) * D + d];
        comb[(size_t)layer * 216 * D + idx] = v;
    } else {
        // ---- pack W [K][NCOLS] fp32 row-major -> fragment-linear bf16
        int isW2 = (b >= nbNode + 216 + 256);
        int t = (b - nbNode - 216 - (isW2 ? 256 : 0)) * 256 + tid;
        int layer = t >> 15;           // total = 32768 per layer for both
        int idx = t & 32767;
        int logN = isW2 ? 7 : 8;
        int NCOLS = 1 << logN;
        int k = idx >> logN, n = idx & (NCOLS - 1);
        int k0 = k >> 5, kq = k & 31, q = kq >> 3, j = kq & 7;
        int tt = n >> 4, ln = n & 15;
        size_t dest = (((size_t)k0 * (NCOLS >> 4) + tt) << 9) + ((q << 4) + ln) * 8 + j;
        const float* W = (isW2 ? W2 : W1) + (size_t)layer * 32768;
        unsigned short* Wp = (isW2 ? w2p : w1p) + (size_t)layer * 32768;
        Wp[dest] = f2bf(W[idx]);
    }
}

// ---------------------------------------------------------------------------
// Single-pass 1024-way partition: edges -> 1024 sub-slice lists directly.
// Packed entry: src(17) | comb_idx<<17 (8) | local_dst<<25 (7).
__global__ __launch_bounds__(256)
void partition_kernel(const int* __restrict__ ei, const int* __restrict__ ea,
                      unsigned int* __restrict__ subL, int* __restrict__ tail2,
                      int E, int N, unsigned long long magic, int ntiles, int nblocks) {
    __shared__ int lcnt[1024], lbase[1024];
    const int tid = threadIdx.x;
    for (int tile = blockIdx.x; tile < ntiles; tile += nblocks) {
        const int tb = tile * 4096;
#pragma unroll
        for (int i = 0; i < 4; ++i) lcnt[tid + i * 256] = 0;
        __syncthreads();
        int sub[16];
        unsigned int entry[16];
#pragma unroll
        for (int j = 0; j < 16; ++j) {
            int e = tb + j * 256 + tid;
            if (e < E) {
                int dst = ei[E + e];
                int c = (ea[3 * e] * 6 + ea[3 * e + 1]) * 6 + ea[3 * e + 2];
                int k = magdiv((unsigned)dst * 1024u, magic);
                int lo = (int)(((long long)k * N + 1023) >> 10);
                sub[j] = k;
                entry[j] = (unsigned int)ei[e] | ((unsigned int)c << 17) |
                           ((unsigned int)(dst - lo) << 25);
                atomicAdd(&lcnt[k], 1);
            } else {
                sub[j] = -1;
            }
        }
        __syncthreads();
#pragma unroll
        for (int i = 0; i < 4; ++i) {
            int k = tid + i * 256;
            int c = lcnt[k];
            if (c) lbase[k] = atomicAdd(&tail2[k], c);
            lcnt[k] = 0;
        }
        __syncthreads();
#pragma unroll
        for (int j = 0; j < 16; ++j) {
            if (sub[j] >= 0) {
                int k = sub[j];
                int pos = lbase[k] + atomicAdd(&lcnt[k], 1);
                if (pos < CAP2) subL[(size_t)k * CAP2 + pos] = entry[j];
            }
        }
        __syncthreads();
    }
}

// ---------------------------------------------------------------------------
// Exclusive scan of 1024 sub-slice tails -> subbase; offsets[N] = E.
__global__ __launch_bounds__(1024)
void subscan_kernel(const int* __restrict__ tail2, int* __restrict__ subbase,
                    int* __restrict__ offsets, int N) {
    const int tid = threadIdx.x, lane = tid & 63, wid = tid >> 6;
    int v = min(tail2[tid], CAP2);
    int s = v;
#pragma unroll
    for (int off = 1; off < 64; off <<= 1) {
        int t = __shfl_up(s, off, 64);
        if (lane >= off) s += t;
    }
    __shared__ int ws[16];
    if (lane == 63) ws[wid] = s;
    __syncthreads();
    if (wid == 0) {
        int w = (lane < 16) ? ws[lane] : 0;
#pragma unroll
        for (int off = 1; off < 16; off <<= 1) {
            int t = __shfl_up(w, off, 64);
            if (lane >= off) w += t;
        }
        if (lane < 16) ws[lane] = w;
    }
    __syncthreads();
    int excl = (wid ? ws[wid - 1] : 0) + s - v;
    subbase[tid] = excl;
    if (tid == 1023) offsets[N] = excl + v;
}

// ---------------------------------------------------------------------------
// One block per sub-slice: LDS counting sort -> contiguous coalesced writes of
// bucket + offsets. No global scatter, no global cursor atomics.
__global__ __launch_bounds__(256)
void csr_sort_kernel(const unsigned int* __restrict__ subL, const int* __restrict__ tail2,
                     const int* __restrict__ subbase, int* __restrict__ offsets,
                     int* __restrict__ bucket, int N) {
    const int k = blockIdx.x;
    const int tid = threadIdx.x, lane = tid & 63, wid = tid >> 6;
    const int len = min(tail2[k], CAP2);
    const int base = subbase[k];
    const int lo = (int)(((long long)k * N + 1023) >> 10);
    const int hi = (int)(((long long)(k + 1) * N + 1023) >> 10);
    const int nn = hi - lo;  // <= 128
    __shared__ int cnt[128], loff[128], wsum[4];
    __shared__ unsigned int sorted[CAP2];
    const unsigned int* src = subL + (size_t)k * CAP2;

    if (tid < 128) cnt[tid] = 0;
    __syncthreads();
    for (int i = tid; i < len; i += 256) atomicAdd(&cnt[src[i] >> 25], 1);
    __syncthreads();
    // exclusive scan of cnt[0..127] (first 2 waves meaningful)
    int v = (tid < 128) ? cnt[tid] : 0;
    int s = v;
#pragma unroll
    for (int off = 1; off < 64; off <<= 1) {
        int t = __shfl_up(s, off, 64);
        if (lane >= off) s += t;
    }
    if (lane == 63) wsum[wid] = s;
    __syncthreads();
    if (tid < 128) loff[tid] = ((wid == 1) ? wsum[0] : 0) + s - v;
    __syncthreads();
    if (tid < nn) offsets[lo + tid] = base + loff[tid];
    if (tid < 128) cnt[tid] = 0;
    __syncthreads();
    for (int i = tid; i < len; i += 256) {
        unsigned int e = src[i];
        int ld = e >> 25;
        int pos = loff[ld] + atomicAdd(&cnt[ld], 1);
        sorted[pos] = e & 0x1FFFFFFu;
    }
    __syncthreads();
    for (int i = tid; i < len; i += 256) bucket[base + i] = (int)sorted[i];
}

// ---------------------------------------------------------------------------
// pre[n] = bf16( (1+eps)*h[n] + sum_{e in in(n)} relu(h[src_e] + comb[c_e]) )
// 16 threads/node, 4-edge unroll (8 loads in flight). comb fp32 (L2-hot).
// Measured pattern floor: ~68.5 us, FETCH 187 MB @ ~2.7 TB/s random-granule.
__global__ __launch_bounds__(256)
void gather_reduce_kernel(const int* __restrict__ offsets, const int* __restrict__ bucket,
                          const float* __restrict__ comb,
                          const unsigned short* __restrict__ hb,
                          const float* __restrict__ eps_l,
                          unsigned short* __restrict__ pre, int N) {
    int gid = blockIdx.x * blockDim.x + threadIdx.x;
    int node = gid >> 4;
    if (node >= N) return;
    int d0 = (gid & 15) * 8;

    union U8 { int4 i; unsigned short u[8]; };
    union C8 { float4 v[2]; float f[8]; };
    float s = 1.0f + eps_l[0];
    float a[8];
    {
        U8 hv; hv.i = *(const int4*)(hb + (size_t)node * D + d0);
#pragma unroll
        for (int j = 0; j < 8; ++j) a[j] = bf2f(hv.u[j]) * s;
    }
    const int beg = offsets[node], end = offsets[node + 1];
    for (int p = beg; p < end; p += 4) {
        int rem = end - p;
        int pk0 = bucket[p];
        int pk1 = bucket[rem > 1 ? p + 1 : p];
        int pk2 = bucket[rem > 2 ? p + 2 : p];
        int pk3 = bucket[rem > 3 ? p + 3 : p];
        U8 h0, h1, h2, h3;
        C8 c0, c1, c2, c3;
        h0.i = *(const int4*)(hb + (size_t)(pk0 & 0x1FFFF) * D + d0);
        c0.v[0] = *(const float4*)(comb + (size_t)(pk0 >> 17) * D + d0);
        c0.v[1] = *(const float4*)(comb + (size_t)(pk0 >> 17) * D + d0 + 4);
        h1.i = *(const int4*)(hb + (size_t)(pk1 & 0x1FFFF) * D + d0);
        c1.v[0] = *(const float4*)(comb + (size_t)(pk1 >> 17) * D + d0);
        c1.v[1] = *(const float4*)(comb + (size_t)(pk1 >> 17) * D + d0 + 4);
        h2.i = *(const int4*)(hb + (size_t)(pk2 & 0x1FFFF) * D + d0);
        c2.v[0] = *(const float4*)(comb + (size_t)(pk2 >> 17) * D + d0);
        c2.v[1] = *(const float4*)(comb + (size_t)(pk2 >> 17) * D + d0 + 4);
        h3.i = *(const int4*)(hb + (size_t)(pk3 & 0x1FFFF) * D + d0);
        c3.v[0] = *(const float4*)(comb + (size_t)(pk3 >> 17) * D + d0);
        c3.v[1] = *(const float4*)(comb + (size_t)(pk3 >> 17) * D + d0 + 4);
#pragma unroll
        for (int j = 0; j < 8; ++j) a[j] += fmaxf(bf2f(h0.u[j]) + c0.f[j], 0.0f);
        if (rem > 1) {
#pragma unroll
            for (int j = 0; j < 8; ++j) a[j] += fmaxf(bf2f(h1.u[j]) + c1.f[j], 0.0f);
        }
        if (rem > 2) {
#pragma unroll
            for (int j = 0; j < 8; ++j) a[j] += fmaxf(bf2f(h2.u[j]) + c2.f[j], 0.0f);
        }
        if (rem > 3) {
#pragma unroll
            for (int j = 0; j < 8; ++j) a[j] += fmaxf(bf2f(h3.u[j]) + c3.f[j], 0.0f);
        }
    }
    U8 o;
#pragma unroll
    for (int j = 0; j < 8; ++j) o.u[j] = f2bf(a[j]);
    *(int4*)(pre + (size_t)node * D + d0) = o.i;
}

// ---------------------------------------------------------------------------
// MFMA GEMM, B staged in LDS (2 x 32KB phases), A prefetched.
// Epilogue: C-tile staged in LDS (reusing Ws, +8-short row pad) -> fully
// coalesced int4 stores (8/thread) into a contiguous 64xNCOLS block region
// (R7 theory: 64x 2-byte scattered stores/thread were the GEMM cost).
// Stats: block sums in LDS -> atomicAdd into gacc copy (blockIdx & 63);
// 64 copies cap same-address atomic chains (R6 lesson).
template <int K, int NCOLS, int TRANSFORM>
__global__ __launch_bounds__(256)
void mfma_gemm_kernel(const unsigned short* __restrict__ A,
                      const unsigned short* __restrict__ Wp,
                      const float* __restrict__ bias,
                      const float* __restrict__ tscale, const float* __restrict__ tshift,
                      unsigned short* __restrict__ Cbf,
                      float* __restrict__ gacc, int M) {
    constexpr int NT = NCOLS / 16;
    constexpr int NCHUNK = K / 32;
    constexpr int CPP = NCHUNK / 2;
    constexpr int CTS = NCOLS + 8;  // padded ctile row stride (16B-aligned, bank-rotated)
    constexpr int WS_SH = (64 * CTS > 16384) ? 64 * CTS : 16384;
    __shared__ unsigned short Ws[WS_SH];
    __shared__ float red[NCOLS * 2];

    const int tid = threadIdx.x;
    const int wave = tid >> 6, lane = tid & 63;
    const int quad = lane >> 4, ln = lane & 15;
    const int m_base = blockIdx.x * 64 + wave * 16;
    int arow = m_base + ln;
    if (arow >= M) arow = M - 1;
    const int kq = quad * 8;

    int4 araw[NCHUNK];
#pragma unroll
    for (int c = 0; c < NCHUNK; ++c)
        araw[c] = *(const int4*)(A + (size_t)arow * K + c * 32 + kq);

    for (int i = tid; i < NCOLS * 2; i += 256) red[i] = 0.f;

    floatx4 acc[NT];
#pragma unroll
    for (int t = 0; t < NT; ++t) acc[t] = (floatx4){0.f, 0.f, 0.f, 0.f};

#pragma unroll
    for (int ph = 0; ph < 2; ++ph) {
        if (ph) __syncthreads();
#pragma unroll
        for (int i = 0; i < 16384; i += 2048)
            *(int4*)&Ws[i + tid * 8] = *(const int4*)&Wp[ph * 16384 + i + tid * 8];
        __syncthreads();
#pragma unroll
        for (int cc = 0; cc < CPP; ++cc) {
            const int c = ph * CPP + cc;
            short8 afrag;
            if constexpr (TRANSFORM) {
                union { int4 i; unsigned short u[8]; } raw;
                raw.i = araw[c];
                const int kb = c * 32 + kq;
                float4 sc0 = *(const float4*)(tscale + kb);
                float4 sc1 = *(const float4*)(tscale + kb + 4);
                float4 sh0 = *(const float4*)(tshift + kb);
                float4 sh1 = *(const float4*)(tshift + kb + 4);
                union { short8 v; unsigned short u[8]; } au;
                au.u[0] = f2bf(fmaxf(bf2f(raw.u[0]) * sc0.x + sh0.x, 0.f));
                au.u[1] = f2bf(fmaxf(bf2f(raw.u[1]) * sc0.y + sh0.y, 0.f));
                au.u[2] = f2bf(fmaxf(bf2f(raw.u[2]) * sc0.z + sh0.z, 0.f));
                au.u[3] = f2bf(fmaxf(bf2f(raw.u[3]) * sc0.w + sh0.w, 0.f));
                au.u[4] = f2bf(fmaxf(bf2f(raw.u[4]) * sc1.x + sh1.x, 0.f));
                au.u[5] = f2bf(fmaxf(bf2f(raw.u[5]) * sc1.y + sh1.y, 0.f));
                au.u[6] = f2bf(fmaxf(bf2f(raw.u[6]) * sc1.z + sh1.z, 0.f));
                au.u[7] = f2bf(fmaxf(bf2f(raw.u[7]) * sc1.w + sh1.w, 0.f));
                afrag = au.v;
            } else {
                afrag = __builtin_bit_cast(short8, araw[c]);
            }
#pragma unroll
            for (int t = 0; t < NT; ++t) {
                short8 bfrag = *(const short8*)&Ws[(((cc * NT) + t) << 9) + lane * 8];
                acc[t] = __builtin_amdgcn_mfma_f32_16x16x32_bf16(afrag, bfrag, acc[t], 0, 0, 0);
            }
        }
    }

    __syncthreads();  // all waves done reading Ws before reuse as ctile
#pragma unroll
    for (int t = 0; t < NT; ++t) {
        int col = t * 16 + ln;
        float bv = bias[col];
        float sv = 0.f, qv = 0.f;
#pragma unroll
        for (int r = 0; r < 4; ++r) {
            int lrow = wave * 16 + quad * 4 + r;
            float v = acc[t][r] + bv;
            Ws[lrow * CTS + col] = f2bf(v);
            if (m_base + quad * 4 + r < M) { sv += v; qv += v * v; }
        }
        sv += __shfl_xor(sv, 16, 64); sv += __shfl_xor(sv, 32, 64);
        qv += __shfl_xor(qv, 16, 64); qv += __shfl_xor(qv, 32, 64);
        if (quad == 0) {
            atomicAdd(&red[col], sv);
            atomicAdd(&red[NCOLS + col], qv);
        }
    }
    __syncthreads();
    // coalesced C write: contiguous 64*NCOLS shorts per block
    {
        constexpr int RI4 = NCOLS / 8;         // int4 chunks per row
        const int row0 = blockIdx.x * 64;
        unsigned short* cb = Cbf + (size_t)row0 * NCOLS;
        for (int i = tid; i < 64 * RI4; i += 256) {
            int row = i / RI4, cc = i - row * RI4;
            if (row0 + row < M)
                *(int4*)(cb + (size_t)i * 8) = *(const int4*)&Ws[row * CTS + cc * 8];
        }
    }
    float* gout = gacc + (size_t)(blockIdx.x & (NCOPY - 1)) * (NCOLS * 2);
    for (int i = tid; i < NCOLS * 2; i += 256) atomicAdd(&gout[i], red[i]);
}

// ---------------------------------------------------------------------------
// One block: reduce 64 gacc copies -> scale/shift; re-zero copies for reuse.
template <int NCOLS>
__global__ void stats_final_kernel(float* __restrict__ gacc,
                                   const float* __restrict__ g, const float* __restrict__ b,
                                   float* __restrict__ scale, float* __restrict__ shift,
                                   float invN) {
    int col = threadIdx.x;
    if (col < NCOLS) {
        float s = 0.f, q = 0.f;
        for (int c = 0; c < NCOPY; ++c) {
            float* p = gacc + (size_t)c * (NCOLS * 2);
            s += p[col];
            q += p[NCOLS + col];
            p[col] = 0.f;
            p[NCOLS + col] = 0.f;
        }
        float mean = s * invN;
        float var = q * invN - mean * mean;
        float inv = 1.0f / sqrtf(var + BN_EPS);
        float sc = g[col] * inv;
        scale[col] = sc;
        shift[col] = b[col] - mean * sc;
    }
}

// ---------------------------------------------------------------------------
// Reads bf16 raw out2. mode 0: hb = bf16(relu(bn(x))); mode 1: h = bn(x) fp32.
__global__ void bn_apply_kernel(const unsigned short* __restrict__ Xb,
                                float* __restrict__ Yf, unsigned short* __restrict__ Yb,
                                const float* __restrict__ scale, const float* __restrict__ shift,
                                int N, int mode) {
    int gid = blockIdx.x * blockDim.x + threadIdx.x;
    int node = gid >> 5;
    if (node >= N) return;
    int d0 = (gid & 31) * 4;
    ushort4 b = *(const ushort4*)(Xb + (size_t)node * D + d0);
    float4 v;
    v.x = bf2f(b.x); v.y = bf2f(b.y); v.z = bf2f(b.z); v.w = bf2f(b.w);
    float4 sc = *(const float4*)(scale + d0);
    float4 sh = *(const float4*)(shift + d0);
    float4 o;
    o.x = v.x * sc.x + sh.x;
    o.y = v.y * sc.y + sh.y;
    o.z = v.z * sc.z + sh.z;
    o.w = v.w * sc.w + sh.w;
    if (mode == 0) {
        ushort4 ob;
        ob.x = f2bf(fmaxf(o.x, 0.f));
        ob.y = f2bf(fmaxf(o.y, 0.f));
        ob.z = f2bf(fmaxf(o.z, 0.f));
        ob.w = f2bf(fmaxf(o.w, 0.f));
        *(ushort4*)(Yb + (size_t)node * D + d0) = ob;
    } else {
        *(float4*)(Yf + (size_t)node * D + d0) = o;
    }
}

// ---------------------------------------------------------------------------
extern "C" void kernel_launch(void* const* d_in, const int* in_sizes, int n_in,
                              void* d_out, int out_size, void* d_ws, size_t ws_size,
                              hipStream_t stream) {
    const int*   x        = (const int*)d_in[0];
    const int*   z        = (const int*)d_in[1];
    const int*   ei       = (const int*)d_in[2];
    const int*   ea       = (const int*)d_in[3];
    const float* atom_emb = (const float*)d_in[4];
    const float* z_emb    = (const float*)d_in[5];
    const float* bond_emb = (const float*)d_in[6];
    const float* eps      = (const float*)d_in[7];
    const float* W1       = (const float*)d_in[8];
    const float* b1       = (const float*)d_in[9];
    const float* g1       = (const float*)d_in[10];
    const float* be1      = (const float*)d_in[11];
    const float* W2       = (const float*)d_in[12];
    const float* b2       = (const float*)d_in[13];
    const float* bng      = (const float*)d_in[14];
    const float* bnb      = (const float*)d_in[15];

    const int N = in_sizes[1];
    const int E = in_sizes[3] / 3;

    float* h = (float*)d_out;  // final [N,128] fp32

    const int ngb = (N + 63) / 64;   // GEMM grid
    const unsigned long long magic = ((1ULL << 44) / (unsigned int)N) + 1;  // exact for x < 2^27

    char* ws = (char*)d_ws;
    size_t off = 0;
    auto alloc = [&](size_t bytes) { void* p = ws + off; off += (bytes + 255) & ~(size_t)255; return p; };
    unsigned short* pre_bf = (unsigned short*)alloc((size_t)N * D * 2);      // 25.6 MB
    unsigned short* out2_bf = pre_bf;            // gemm2 raw output (pre is dead by then)
    unsigned short* out1_bf = (unsigned short*)alloc((size_t)N * 2 * D * 2); // 51.2 MB
    unsigned short* hb      = (unsigned short*)alloc((size_t)N * D * 2);     // 25.6 MB
    int* offsets = (int*)alloc((size_t)(N + 1) * 4);
    int* bucket  = (int*)alloc((size_t)E * 4);
    unsigned int* subL = (unsigned int*)alloc((size_t)NSUB * CAP2 * 4); // 8 MB
    int* subbase = (int*)alloc(NSUB * 4);
    float* stats = (float*)alloc(1024 * 4);                       // scale/shift outputs
    // gstats (64 copies x 768) + tail2 (1024 ints) contiguous: ONE memset
    float* gstats = (float*)alloc(((size_t)NCOPY * 768 + 1024) * 4);
    unsigned short* w1p  = (unsigned short*)alloc((size_t)2 * D * 2 * D * 2);
    unsigned short* w2p  = (unsigned short*)alloc((size_t)2 * 2 * D * D * 2);
    float* comb = (float*)alloc((size_t)2 * 216 * D * 4);    // fp32 comb, 221 KB

    float* scale1 = stats;          // 256
    float* shift1 = stats + 256;    // 256
    float* scale2 = stats + 512;    // 128
    float* shift2 = stats + 640;    // 128
    float* gacc1 = gstats;                          // NCOPY x 512
    float* gacc2 = gstats + (size_t)NCOPY * 512;    // NCOPY x 256
    int* tail2 = (int*)(gstats + (size_t)NCOPY * 768);  // 1024 ints

    const float invN = 1.0f / (float)N;
    const int ntiles = (E + 4095) / 4096;
    const int nbNode = (N * 32 + 255) / 256;

    // --- CSR build: single-pass 1024-way partition -> subscan -> LDS sort ---
    hipMemsetAsync(gstats, 0, ((size_t)NCOPY * 768 + 1024) * sizeof(float), stream);
    partition_kernel<<<256, 256, 0, stream>>>(ei, ea, subL, tail2, E, N, magic, ntiles, 256);
    subscan_kernel<<<1, 1024, 0, stream>>>(tail2, subbase, offsets, N);
    csr_sort_kernel<<<NSUB, 256, 0, stream>>>(subL, tail2, subbase, offsets, bucket, N);

    // --- merged setup: node_init + comb + pack_w1 + pack_w2 ---
    setup_kernel<<<nbNode + 216 + 256 + 256, 256, 0, stream>>>(
        x, z, atom_emb, z_emb, hb, N, nbNode, bond_emb, comb, W1, w1p, W2, w2p);

    for (int l = 0; l < 2; ++l) {
        gather_reduce_kernel<<<(N * 16 + 255) / 256, 256, 0, stream>>>(
            offsets, bucket, comb + (size_t)l * 216 * D, hb, eps + l, pre_bf, N);

        mfma_gemm_kernel<128, 256, 0><<<ngb, 256, 0, stream>>>(
            pre_bf, w1p + (size_t)l * D * 2 * D, b1 + (size_t)l * 2 * D,
            nullptr, nullptr, out1_bf, gacc1, N);
        stats_final_kernel<256><<<1, 256, 0, stream>>>(
            gacc1, g1 + (size_t)l * 2 * D, be1 + (size_t)l * 2 * D, scale1, shift1, invN);

        mfma_gemm_kernel<256, 128, 1><<<ngb, 256, 0, stream>>>(
            out1_bf, w2p + (size_t)l * 2 * D * D, b2 + (size_t)l * D,
            scale1, shift1, out2_bf, gacc2, N);
        stats_final_kernel<128><<<1, 128, 0, stream>>>(
            gacc2, bng + (size_t)l * D, bnb + (size_t)l * D, scale2, shift2, invN);

        bn_apply_kernel<<<(N * 32 + 255) / 256, 256, 0, stream>>>(
            out2_bf, h, hb, scale2, shift2, N, l == 0 ? 0 : 1);
    }
}

// Round 10
// 483.709 us; speedup vs baseline: 1.2476x; 1.0393x over previous
//
#include <hip/hip_runtime.h>

#define D 128
#define BN_EPS 1e-5f
#define NSUB 1024
#define CAP2 2048
#define NCOPY 64   // stats accumulator copies (kills same-address atomic chains)

typedef __attribute__((ext_vector_type(8))) short short8;   // 8 x bf16 (4 VGPRs)
typedef __attribute__((ext_vector_type(4))) float floatx4;  // MFMA accumulator

__device__ __forceinline__ float bf2f(unsigned short u) {
    unsigned int x = ((unsigned int)u) << 16;
    return __builtin_bit_cast(float, x);
}
__device__ __forceinline__ unsigned short f2bf(float f) {
    unsigned int x = __builtin_bit_cast(unsigned int, f);
    x = x + 0x7FFFu + ((x >> 16) & 1u);  // round-to-nearest-even
    return (unsigned short)(x >> 16);
}
// exact floor(x / N) for x < 2^27 via host magic M = 2^44/N + 1 (N < 2^17)
__device__ __forceinline__ int magdiv(unsigned int x, unsigned long long magic) {
    return (int)(((unsigned long long)x * magic) >> 44);
}

// ---------------------------------------------------------------------------
// Single-pass 1024-way partition: edges -> 1024 sub-slice lists directly.
// Packed entry: src(17) | comb_idx<<17 (8) | local_dst<<25 (7).
__global__ __launch_bounds__(256)
void partition_kernel(const int* __restrict__ ei, const int* __restrict__ ea,
                      unsigned int* __restrict__ subL, int* __restrict__ tail2,
                      int E, int N, unsigned long long magic, int ntiles, int nblocks) {
    __shared__ int lcnt[1024], lbase[1024];
    const int tid = threadIdx.x;
    for (int tile = blockIdx.x; tile < ntiles; tile += nblocks) {
        const int tb = tile * 4096;
#pragma unroll
        for (int i = 0; i < 4; ++i) lcnt[tid + i * 256] = 0;
        __syncthreads();
        int sub[16];
        unsigned int entry[16];
#pragma unroll
        for (int j = 0; j < 16; ++j) {
            int e = tb + j * 256 + tid;
            if (e < E) {
                int dst = ei[E + e];
                int c = (ea[3 * e] * 6 + ea[3 * e + 1]) * 6 + ea[3 * e + 2];
                int k = magdiv((unsigned)dst * 1024u, magic);
                int lo = (int)(((long long)k * N + 1023) >> 10);
                sub[j] = k;
                entry[j] = (unsigned int)ei[e] | ((unsigned int)c << 17) |
                           ((unsigned int)(dst - lo) << 25);
                atomicAdd(&lcnt[k], 1);
            } else {
                sub[j] = -1;
            }
        }
        __syncthreads();
#pragma unroll
        for (int i = 0; i < 4; ++i) {
            int k = tid + i * 256;
            int c = lcnt[k];
            if (c) lbase[k] = atomicAdd(&tail2[k], c);
            lcnt[k] = 0;
        }
        __syncthreads();
#pragma unroll
        for (int j = 0; j < 16; ++j) {
            if (sub[j] >= 0) {
                int k = sub[j];
                int pos = lbase[k] + atomicAdd(&lcnt[k], 1);
                if (pos < CAP2) subL[(size_t)k * CAP2 + pos] = entry[j];
            }
        }
        __syncthreads();
    }
}

// ---------------------------------------------------------------------------
// Exclusive scan of 1024 sub-slice tails -> subbase; offsets[N] = E.
__global__ __launch_bounds__(1024)
void subscan_kernel(const int* __restrict__ tail2, int* __restrict__ subbase,
                    int* __restrict__ offsets, int N) {
    const int tid = threadIdx.x, lane = tid & 63, wid = tid >> 6;
    int v = min(tail2[tid], CAP2);
    int s = v;
#pragma unroll
    for (int off = 1; off < 64; off <<= 1) {
        int t = __shfl_up(s, off, 64);
        if (lane >= off) s += t;
    }
    __shared__ int ws[16];
    if (lane == 63) ws[wid] = s;
    __syncthreads();
    if (wid == 0) {
        int w = (lane < 16) ? ws[lane] : 0;
#pragma unroll
        for (int off = 1; off < 16; off <<= 1) {
            int t = __shfl_up(w, off, 64);
            if (lane >= off) w += t;
        }
        if (lane < 16) ws[lane] = w;
    }
    __syncthreads();
    int excl = (wid ? ws[wid - 1] : 0) + s - v;
    subbase[tid] = excl;
    if (tid == 1023) offsets[N] = excl + v;
}

// ---------------------------------------------------------------------------
// Merged: blocks [0,NSUB) do the per-sub-slice LDS counting sort (CSR build);
// blocks [NSUB,...) do setup (node_init + comb fp32 + pack_w1 + pack_w2).
// Independent work -> one dispatch.
__global__ __launch_bounds__(256)
void sort_setup_kernel(const unsigned int* __restrict__ subL, const int* __restrict__ tail2,
                       const int* __restrict__ subbase, int* __restrict__ offsets,
                       int* __restrict__ bucket, int N,
                       const int* __restrict__ x, const int* __restrict__ z,
                       const float* __restrict__ atom_emb, const float* __restrict__ z_emb,
                       unsigned short* __restrict__ hb, int nbNode,
                       const float* __restrict__ bond_emb, float* __restrict__ comb,
                       const float* __restrict__ W1, unsigned short* __restrict__ w1p,
                       const float* __restrict__ W2, unsigned short* __restrict__ w2p) {
    __shared__ int cnt[128], loff[128], wsum[4];
    __shared__ unsigned int sorted[CAP2];
    const int tid = threadIdx.x;
    if (blockIdx.x < NSUB) {
        // ---- csr_sort ----
        const int k = blockIdx.x;
        const int lane = tid & 63, wid = tid >> 6;
        const int len = min(tail2[k], CAP2);
        const int base = subbase[k];
        const int lo = (int)(((long long)k * N + 1023) >> 10);
        const int hi = (int)(((long long)(k + 1) * N + 1023) >> 10);
        const int nn = hi - lo;  // <= 128
        const unsigned int* src = subL + (size_t)k * CAP2;

        if (tid < 128) cnt[tid] = 0;
        __syncthreads();
        for (int i = tid; i < len; i += 256) atomicAdd(&cnt[src[i] >> 25], 1);
        __syncthreads();
        int v = (tid < 128) ? cnt[tid] : 0;
        int s = v;
#pragma unroll
        for (int off = 1; off < 64; off <<= 1) {
            int t = __shfl_up(s, off, 64);
            if (lane >= off) s += t;
        }
        if (lane == 63) wsum[wid] = s;
        __syncthreads();
        if (tid < 128) loff[tid] = ((wid == 1) ? wsum[0] : 0) + s - v;
        __syncthreads();
        if (tid < nn) offsets[lo + tid] = base + loff[tid];
        if (tid < 128) cnt[tid] = 0;
        __syncthreads();
        for (int i = tid; i < len; i += 256) {
            unsigned int e = src[i];
            int ld = e >> 25;
            int pos = loff[ld] + atomicAdd(&cnt[ld], 1);
            sorted[pos] = e & 0x1FFFFFFu;
        }
        __syncthreads();
        for (int i = tid; i < len; i += 256) bucket[base + i] = (int)sorted[i];
        return;
    }
    const int b = blockIdx.x - NSUB;
    if (b < nbNode) {
        // ---- node_init: hb0 = bf16( sum_f atom_emb[f,x[n,f],:] + z_emb[z[n],:] )
        int gid = b * 256 + tid;
        int node = gid >> 5;
        if (node >= N) return;
        int d0 = (gid & 31) * 4;
        float4 acc = *(const float4*)(z_emb + (size_t)z[node] * D + d0);
#pragma unroll
        for (int f = 0; f < 9; ++f) {
            int v = x[node * 9 + f];
            const float4 t = *(const float4*)(atom_emb + (size_t)(f * 119 + v) * D + d0);
            acc.x += t.x; acc.y += t.y; acc.z += t.z; acc.w += t.w;
        }
        ushort4 o;
        o.x = f2bf(acc.x); o.y = f2bf(acc.y); o.z = f2bf(acc.z); o.w = f2bf(acc.w);
        *(ushort4*)(hb + (size_t)node * D + d0) = o;
    } else if (b < nbNode + 216) {
        // ---- comb[layer][c][d] = b0[a0][d]+b1[a1][d]+b2[a2][d]  (fp32, L2-resident)
        int t = (b - nbNode) * 256 + tid;
        int layer = t / (216 * D);
        int idx = t - layer * (216 * D);
        int c = idx >> 7, d = idx & 127;
        int a0 = c / 36, a1 = (c / 6) % 6, a2 = c % 6;
        const float* bb = bond_emb + (size_t)layer * 3 * 6 * D;
        float v = bb[(0 * 6 + a0) * D + d] + bb[(1 * 6 + a1) * D + d] + bb[(2 * 6 + a2) * D + d];
        comb[(size_t)layer * 216 * D + idx] = v;
    } else {
        // ---- pack W [K][NCOLS] fp32 row-major -> fragment-linear bf16
        int isW2 = (b >= nbNode + 216 + 256);
        int t = (b - nbNode - 216 - (isW2 ? 256 : 0)) * 256 + tid;
        int layer = t >> 15;           // total = 32768 per layer for both
        int idx = t & 32767;
        int logN = isW2 ? 7 : 8;
        int NCOLS = 1 << logN;
        int k = idx >> logN, n = idx & (NCOLS - 1);
        int k0 = k >> 5, kq = k & 31, q = kq >> 3, j = kq & 7;
        int tt = n >> 4, ln = n & 15;
        size_t dest = (((size_t)k0 * (NCOLS >> 4) + tt) << 9) + ((q << 4) + ln) * 8 + j;
        const float* W = (isW2 ? W2 : W1) + (size_t)layer * 32768;
        unsigned short* Wp = (isW2 ? w2p : w1p) + (size_t)layer * 32768;
        Wp[dest] = f2bf(W[idx]);
    }
}

// ---------------------------------------------------------------------------
// pre[n] = bf16( (1+eps)*h[n] + sum_{e in in(n)} relu(h[src_e] + comb[c_e]) )
// 16 threads/node, 4-edge unroll (8 loads in flight). comb fp32 (L2-hot).
// Measured pattern floor: ~68.5 us, FETCH 187 MB @ ~2.7 TB/s random-granule.
__global__ __launch_bounds__(256)
void gather_reduce_kernel(const int* __restrict__ offsets, const int* __restrict__ bucket,
                          const float* __restrict__ comb,
                          const unsigned short* __restrict__ hb,
                          const float* __restrict__ eps_l,
                          unsigned short* __restrict__ pre, int N) {
    int gid = blockIdx.x * blockDim.x + threadIdx.x;
    int node = gid >> 4;
    if (node >= N) return;
    int d0 = (gid & 15) * 8;

    union U8 { int4 i; unsigned short u[8]; };
    union C8 { float4 v[2]; float f[8]; };
    float s = 1.0f + eps_l[0];
    float a[8];
    {
        U8 hv; hv.i = *(const int4*)(hb + (size_t)node * D + d0);
#pragma unroll
        for (int j = 0; j < 8; ++j) a[j] = bf2f(hv.u[j]) * s;
    }
    const int beg = offsets[node], end = offsets[node + 1];
    for (int p = beg; p < end; p += 4) {
        int rem = end - p;
        int pk0 = bucket[p];
        int pk1 = bucket[rem > 1 ? p + 1 : p];
        int pk2 = bucket[rem > 2 ? p + 2 : p];
        int pk3 = bucket[rem > 3 ? p + 3 : p];
        U8 h0, h1, h2, h3;
        C8 c0, c1, c2, c3;
        h0.i = *(const int4*)(hb + (size_t)(pk0 & 0x1FFFF) * D + d0);
        c0.v[0] = *(const float4*)(comb + (size_t)(pk0 >> 17) * D + d0);
        c0.v[1] = *(const float4*)(comb + (size_t)(pk0 >> 17) * D + d0 + 4);
        h1.i = *(const int4*)(hb + (size_t)(pk1 & 0x1FFFF) * D + d0);
        c1.v[0] = *(const float4*)(comb + (size_t)(pk1 >> 17) * D + d0);
        c1.v[1] = *(const float4*)(comb + (size_t)(pk1 >> 17) * D + d0 + 4);
        h2.i = *(const int4*)(hb + (size_t)(pk2 & 0x1FFFF) * D + d0);
        c2.v[0] = *(const float4*)(comb + (size_t)(pk2 >> 17) * D + d0);
        c2.v[1] = *(const float4*)(comb + (size_t)(pk2 >> 17) * D + d0 + 4);
        h3.i = *(const int4*)(hb + (size_t)(pk3 & 0x1FFFF) * D + d0);
        c3.v[0] = *(const float4*)(comb + (size_t)(pk3 >> 17) * D + d0);
        c3.v[1] = *(const float4*)(comb + (size_t)(pk3 >> 17) * D + d0 + 4);
#pragma unroll
        for (int j = 0; j < 8; ++j) a[j] += fmaxf(bf2f(h0.u[j]) + c0.f[j], 0.0f);
        if (rem > 1) {
#pragma unroll
            for (int j = 0; j < 8; ++j) a[j] += fmaxf(bf2f(h1.u[j]) + c1.f[j], 0.0f);
        }
        if (rem > 2) {
#pragma unroll
            for (int j = 0; j < 8; ++j) a[j] += fmaxf(bf2f(h2.u[j]) + c2.f[j], 0.0f);
        }
        if (rem > 3) {
#pragma unroll
            for (int j = 0; j < 8; ++j) a[j] += fmaxf(bf2f(h3.u[j]) + c3.f[j], 0.0f);
        }
    }
    U8 o;
#pragma unroll
    for (int j = 0; j < 8; ++j) o.u[j] = f2bf(a[j]);
    *(int4*)(pre + (size_t)node * D + d0) = o.i;
}

// ---------------------------------------------------------------------------
// MFMA GEMM, B staged in LDS (2 x 32KB phases), A prefetched.
// TRANSFORM variant computes its own BN scale/shift in a prologue from the
// previous GEMM's gacc copies (no stats_final dispatch needed).
// Epilogue: C-tile staged in LDS (Ws reuse, +8 pad) -> coalesced int4 stores.
// Stats out: LDS block sums -> atomicAdd into gacc copy (blockIdx & 63).
template <int K, int NCOLS, int TRANSFORM>
__global__ __launch_bounds__(256)
void mfma_gemm_kernel(const unsigned short* __restrict__ A,
                      const unsigned short* __restrict__ Wp,
                      const float* __restrict__ bias,
                      const float* __restrict__ gaccP,   // prev-layer stats copies (TRANSFORM)
                      const float* __restrict__ gam, const float* __restrict__ bet,
                      float invN,
                      unsigned short* __restrict__ Cbf,
                      float* __restrict__ gacc, int M) {
    constexpr int NT = NCOLS / 16;
    constexpr int NCHUNK = K / 32;
    constexpr int CPP = NCHUNK / 2;
    constexpr int CTS = NCOLS + 8;  // padded ctile row stride
    constexpr int WS_SH = (64 * CTS > 16384) ? 64 * CTS : 16384;
    __shared__ unsigned short Ws[WS_SH];
    __shared__ float red[NCOLS * 2];
    __shared__ float tsc_s[TRANSFORM ? K : 1], tsh_s[TRANSFORM ? K : 1];

    const int tid = threadIdx.x;
    const int wave = tid >> 6, lane = tid & 63;
    const int quad = lane >> 4, ln = lane & 15;
    const int m_base = blockIdx.x * 64 + wave * 16;
    int arow = m_base + ln;
    if (arow >= M) arow = M - 1;
    const int kq = quad * 8;

    int4 araw[NCHUNK];
#pragma unroll
    for (int c = 0; c < NCHUNK; ++c)
        araw[c] = *(const int4*)(A + (size_t)arow * K + c * 32 + kq);

    for (int i = tid; i < NCOLS * 2; i += 256) red[i] = 0.f;

    if constexpr (TRANSFORM) {
        // prologue: reduce NCOPY gacc copies -> scale/shift for the K input cols
        for (int col = tid; col < K; col += 256) {
            float s = 0.f, q = 0.f;
            for (int c = 0; c < NCOPY; ++c) {
                const float* p = gaccP + (size_t)c * (K * 2);
                s += p[col];
                q += p[K + col];
            }
            float mean = s * invN;
            float var = q * invN - mean * mean;
            float inv = 1.0f / sqrtf(var + BN_EPS);
            float sc = gam[col] * inv;
            tsc_s[col] = sc;
            tsh_s[col] = bet[col] - mean * sc;
        }
    }

    floatx4 acc[NT];
#pragma unroll
    for (int t = 0; t < NT; ++t) acc[t] = (floatx4){0.f, 0.f, 0.f, 0.f};

#pragma unroll
    for (int ph = 0; ph < 2; ++ph) {
        if (ph) __syncthreads();
#pragma unroll
        for (int i = 0; i < 16384; i += 2048)
            *(int4*)&Ws[i + tid * 8] = *(const int4*)&Wp[ph * 16384 + i + tid * 8];
        __syncthreads();   // also covers tsc_s/tsh_s prologue writes (ph==0)
#pragma unroll
        for (int cc = 0; cc < CPP; ++cc) {
            const int c = ph * CPP + cc;
            short8 afrag;
            if constexpr (TRANSFORM) {
                union { int4 i; unsigned short u[8]; } raw;
                raw.i = araw[c];
                const int kb = c * 32 + kq;
                float4 sc0 = *(const float4*)&tsc_s[kb];
                float4 sc1 = *(const float4*)&tsc_s[kb + 4];
                float4 sh0 = *(const float4*)&tsh_s[kb];
                float4 sh1 = *(const float4*)&tsh_s[kb + 4];
                union { short8 v; unsigned short u[8]; } au;
                au.u[0] = f2bf(fmaxf(bf2f(raw.u[0]) * sc0.x + sh0.x, 0.f));
                au.u[1] = f2bf(fmaxf(bf2f(raw.u[1]) * sc0.y + sh0.y, 0.f));
                au.u[2] = f2bf(fmaxf(bf2f(raw.u[2]) * sc0.z + sh0.z, 0.f));
                au.u[3] = f2bf(fmaxf(bf2f(raw.u[3]) * sc0.w + sh0.w, 0.f));
                au.u[4] = f2bf(fmaxf(bf2f(raw.u[4]) * sc1.x + sh1.x, 0.f));
                au.u[5] = f2bf(fmaxf(bf2f(raw.u[5]) * sc1.y + sh1.y, 0.f));
                au.u[6] = f2bf(fmaxf(bf2f(raw.u[6]) * sc1.z + sh1.z, 0.f));
                au.u[7] = f2bf(fmaxf(bf2f(raw.u[7]) * sc1.w + sh1.w, 0.f));
                afrag = au.v;
            } else {
                afrag = __builtin_bit_cast(short8, araw[c]);
            }
#pragma unroll
            for (int t = 0; t < NT; ++t) {
                short8 bfrag = *(const short8*)&Ws[(((cc * NT) + t) << 9) + lane * 8];
                acc[t] = __builtin_amdgcn_mfma_f32_16x16x32_bf16(afrag, bfrag, acc[t], 0, 0, 0);
            }
        }
    }

    __syncthreads();  // all waves done reading Ws before reuse as ctile
#pragma unroll
    for (int t = 0; t < NT; ++t) {
        int col = t * 16 + ln;
        float bv = bias[col];
        float sv = 0.f, qv = 0.f;
#pragma unroll
        for (int r = 0; r < 4; ++r) {
            int lrow = wave * 16 + quad * 4 + r;
            float v = acc[t][r] + bv;
            Ws[lrow * CTS + col] = f2bf(v);
            if (m_base + quad * 4 + r < M) { sv += v; qv += v * v; }
        }
        sv += __shfl_xor(sv, 16, 64); sv += __shfl_xor(sv, 32, 64);
        qv += __shfl_xor(qv, 16, 64); qv += __shfl_xor(qv, 32, 64);
        if (quad == 0) {
            atomicAdd(&red[col], sv);
            atomicAdd(&red[NCOLS + col], qv);
        }
    }
    __syncthreads();
    // coalesced C write: contiguous 64*NCOLS shorts per block
    {
        constexpr int RI4 = NCOLS / 8;
        const int row0 = blockIdx.x * 64;
        unsigned short* cb = Cbf + (size_t)row0 * NCOLS;
        for (int i = tid; i < 64 * RI4; i += 256) {
            int row = i / RI4, cc = i - row * RI4;
            if (row0 + row < M)
                *(int4*)(cb + (size_t)i * 8) = *(const int4*)&Ws[row * CTS + cc * 8];
        }
    }
    float* gout = gacc + (size_t)(blockIdx.x & (NCOPY - 1)) * (NCOLS * 2);
    for (int i = tid; i < NCOLS * 2; i += 256) atomicAdd(&gout[i], red[i]);
}

// ---------------------------------------------------------------------------
// BN apply with self-computed scale/shift (prologue reduces gacc2 copies).
// Grid-strided (few blocks -> cheap prologue).
// mode 0: hb = bf16(relu(bn(x))); mode 1: h = bn(x) fp32 (final output).
__global__ __launch_bounds__(256)
void bn_apply_kernel(const unsigned short* __restrict__ Xb,
                     float* __restrict__ Yf, unsigned short* __restrict__ Yb,
                     const float* __restrict__ gacc,
                     const float* __restrict__ g, const float* __restrict__ b,
                     float invN, int N, int mode, int nblocks) {
    __shared__ float sc_s[D], sh_s[D];
    const int tid = threadIdx.x;
    if (tid < D) {
        float s = 0.f, q = 0.f;
        for (int c = 0; c < NCOPY; ++c) {
            const float* p = gacc + (size_t)c * (D * 2);
            s += p[tid];
            q += p[D + tid];
        }
        float mean = s * invN;
        float var = q * invN - mean * mean;
        float inv = 1.0f / sqrtf(var + BN_EPS);
        float sc = g[tid] * inv;
        sc_s[tid] = sc;
        sh_s[tid] = b[tid] - mean * sc;
    }
    __syncthreads();
    const int nchunk = (N + 7) / 8;  // 8 nodes per 256-thread chunk
    const int d0 = (tid & 31) * 4;
    for (int chunk = blockIdx.x; chunk < nchunk; chunk += nblocks) {
        int node = chunk * 8 + (tid >> 5);
        if (node >= N) continue;
        ushort4 xb = *(const ushort4*)(Xb + (size_t)node * D + d0);
        float4 v;
        v.x = bf2f(xb.x); v.y = bf2f(xb.y); v.z = bf2f(xb.z); v.w = bf2f(xb.w);
        float4 sc = *(const float4*)&sc_s[d0];
        float4 sh = *(const float4*)&sh_s[d0];
        float4 o;
        o.x = v.x * sc.x + sh.x;
        o.y = v.y * sc.y + sh.y;
        o.z = v.z * sc.z + sh.z;
        o.w = v.w * sc.w + sh.w;
        if (mode == 0) {
            ushort4 ob;
            ob.x = f2bf(fmaxf(o.x, 0.f));
            ob.y = f2bf(fmaxf(o.y, 0.f));
            ob.z = f2bf(fmaxf(o.z, 0.f));
            ob.w = f2bf(fmaxf(o.w, 0.f));
            *(ushort4*)(Yb + (size_t)node * D + d0) = ob;
        } else {
            *(float4*)(Yf + (size_t)node * D + d0) = o;
        }
    }
}

// ---------------------------------------------------------------------------
extern "C" void kernel_launch(void* const* d_in, const int* in_sizes, int n_in,
                              void* d_out, int out_size, void* d_ws, size_t ws_size,
                              hipStream_t stream) {
    const int*   x        = (const int*)d_in[0];
    const int*   z        = (const int*)d_in[1];
    const int*   ei       = (const int*)d_in[2];
    const int*   ea       = (const int*)d_in[3];
    const float* atom_emb = (const float*)d_in[4];
    const float* z_emb    = (const float*)d_in[5];
    const float* bond_emb = (const float*)d_in[6];
    const float* eps      = (const float*)d_in[7];
    const float* W1       = (const float*)d_in[8];
    const float* b1       = (const float*)d_in[9];
    const float* g1       = (const float*)d_in[10];
    const float* be1      = (const float*)d_in[11];
    const float* W2       = (const float*)d_in[12];
    const float* b2       = (const float*)d_in[13];
    const float* bng      = (const float*)d_in[14];
    const float* bnb      = (const float*)d_in[15];

    const int N = in_sizes[1];
    const int E = in_sizes[3] / 3;

    float* h = (float*)d_out;  // final [N,128] fp32

    const int ngb = (N + 63) / 64;   // GEMM grid
    const unsigned long long magic = ((1ULL << 44) / (unsigned int)N) + 1;  // exact for x < 2^27

    char* ws = (char*)d_ws;
    size_t off = 0;
    auto alloc = [&](size_t bytes) { void* p = ws + off; off += (bytes + 255) & ~(size_t)255; return p; };
    unsigned short* pre_bf = (unsigned short*)alloc((size_t)N * D * 2);      // 25.6 MB
    unsigned short* out2_bf = pre_bf;            // gemm2 raw output (pre is dead by then)
    unsigned short* out1_bf = (unsigned short*)alloc((size_t)N * 2 * D * 2); // 51.2 MB
    unsigned short* hb      = (unsigned short*)alloc((size_t)N * D * 2);     // 25.6 MB
    int* offsets = (int*)alloc((size_t)(N + 1) * 4);
    int* bucket  = (int*)alloc((size_t)E * 4);
    unsigned int* subL = (unsigned int*)alloc((size_t)NSUB * CAP2 * 4); // 8 MB
    int* subbase = (int*)alloc(NSUB * 4);
    // per-layer stats copies (no re-zeroing needed): 2x NCOPYx512 + 2x NCOPYx256, + tail2
    float* gstats = (float*)alloc(((size_t)NCOPY * 1536 + 1024) * 4);
    unsigned short* w1p  = (unsigned short*)alloc((size_t)2 * D * 2 * D * 2);
    unsigned short* w2p  = (unsigned short*)alloc((size_t)2 * 2 * D * D * 2);
    float* comb = (float*)alloc((size_t)2 * 216 * D * 4);    // fp32 comb, 221 KB

    float* gacc1base = gstats;                            // [2][NCOPY*512]
    float* gacc2base = gstats + (size_t)2 * NCOPY * 512;  // [2][NCOPY*256]
    int* tail2 = (int*)(gstats + (size_t)NCOPY * 1536);   // 1024 ints

    const float invN = 1.0f / (float)N;
    const int ntiles = (E + 4095) / 4096;
    const int nbNode = (N * 32 + 255) / 256;
    const int nbBN = (N + 63) / 64;   // bn_apply grid (8 chunks each)

    // --- CSR build + setup: partition -> subscan -> merged sort+setup ---
    hipMemsetAsync(gstats, 0, ((size_t)NCOPY * 1536 + 1024) * sizeof(float), stream);
    partition_kernel<<<256, 256, 0, stream>>>(ei, ea, subL, tail2, E, N, magic, ntiles, 256);
    subscan_kernel<<<1, 1024, 0, stream>>>(tail2, subbase, offsets, N);
    sort_setup_kernel<<<NSUB + nbNode + 216 + 512, 256, 0, stream>>>(
        subL, tail2, subbase, offsets, bucket, N,
        x, z, atom_emb, z_emb, hb, nbNode, bond_emb, comb, W1, w1p, W2, w2p);

    for (int l = 0; l < 2; ++l) {
        float* gacc1 = gacc1base + (size_t)l * NCOPY * 512;
        float* gacc2 = gacc2base + (size_t)l * NCOPY * 256;

        gather_reduce_kernel<<<(N * 16 + 255) / 256, 256, 0, stream>>>(
            offsets, bucket, comb + (size_t)l * 216 * D, hb, eps + l, pre_bf, N);

        mfma_gemm_kernel<128, 256, 0><<<ngb, 256, 0, stream>>>(
            pre_bf, w1p + (size_t)l * D * 2 * D, b1 + (size_t)l * 2 * D,
            nullptr, nullptr, nullptr, invN, out1_bf, gacc1, N);

        mfma_gemm_kernel<256, 128, 1><<<ngb, 256, 0, stream>>>(
            out1_bf, w2p + (size_t)l * 2 * D * D, b2 + (size_t)l * D,
            gacc1, g1 + (size_t)l * 2 * D, be1 + (size_t)l * 2 * D, invN,
            out2_bf, gacc2, N);

        bn_apply_kernel<<<nbBN, 256, 0, stream>>>(
            out2_bf, h, hb, gacc2, bng + (size_t)l * D, bnb + (size_t)l * D,
            invN, N, l == 0 ? 0 : 1, nbBN);
    }
}

// Round 11
// 482.426 us; speedup vs baseline: 1.2509x; 1.0027x over previous
//
#include <hip/hip_runtime.h>

#define D 128
#define BN_EPS 1e-5f
#define NSUB 1024
#define CAP2 2048
#define NCOPY 64   // stats accumulator copies (kills same-address atomic chains)

typedef __attribute__((ext_vector_type(8))) short short8;   // 8 x bf16 (4 VGPRs)
typedef __attribute__((ext_vector_type(4))) float floatx4;  // MFMA accumulator

__device__ __forceinline__ float bf2f(unsigned short u) {
    unsigned int x = ((unsigned int)u) << 16;
    return __builtin_bit_cast(float, x);
}
__device__ __forceinline__ unsigned short f2bf(float f) {
    unsigned int x = __builtin_bit_cast(unsigned int, f);
    x = x + 0x7FFFu + ((x >> 16) & 1u);  // round-to-nearest-even
    return (unsigned short)(x >> 16);
}
// exact floor(x / N) for x < 2^27 via host magic M = 2^44/N + 1 (N < 2^17)
__device__ __forceinline__ int magdiv(unsigned int x, unsigned long long magic) {
    return (int)(((unsigned long long)x * magic) >> 44);
}

// ---------------------------------------------------------------------------
// Single-pass 1024-way partition: edges -> 1024 sub-slice lists directly.
// Packed entry: src(17) | comb_idx<<17 (8) | local_dst<<25 (7).
// Tile = 2048 edges, grid = ntiles (R10 finding: 256-block launch was 1
// block/CU = 4 waves/CU for a latency-bound scatter kernel).
__global__ __launch_bounds__(256)
void partition_kernel(const int* __restrict__ ei, const int* __restrict__ ea,
                      unsigned int* __restrict__ subL, int* __restrict__ tail2,
                      int E, int N, unsigned long long magic) {
    __shared__ int lcnt[1024], lbase[1024];
    const int tid = threadIdx.x;
    const int tb = blockIdx.x * 2048;
#pragma unroll
    for (int i = 0; i < 4; ++i) lcnt[tid + i * 256] = 0;
    __syncthreads();
    int sub[8];
    unsigned int entry[8];
#pragma unroll
    for (int j = 0; j < 8; ++j) {
        int e = tb + j * 256 + tid;
        if (e < E) {
            int dst = ei[E + e];
            int c = (ea[3 * e] * 6 + ea[3 * e + 1]) * 6 + ea[3 * e + 2];
            int k = magdiv((unsigned)dst * 1024u, magic);
            int lo = (int)(((long long)k * N + 1023) >> 10);
            sub[j] = k;
            entry[j] = (unsigned int)ei[e] | ((unsigned int)c << 17) |
                       ((unsigned int)(dst - lo) << 25);
            atomicAdd(&lcnt[k], 1);
        } else {
            sub[j] = -1;
        }
    }
    __syncthreads();
#pragma unroll
    for (int i = 0; i < 4; ++i) {
        int k = tid + i * 256;
        int c = lcnt[k];
        if (c) lbase[k] = atomicAdd(&tail2[k], c);
        lcnt[k] = 0;
    }
    __syncthreads();
#pragma unroll
    for (int j = 0; j < 8; ++j) {
        if (sub[j] >= 0) {
            int k = sub[j];
            int pos = lbase[k] + atomicAdd(&lcnt[k], 1);
            if (pos < CAP2) subL[(size_t)k * CAP2 + pos] = entry[j];
        }
    }
}

// ---------------------------------------------------------------------------
// Exclusive scan of 1024 sub-slice tails -> subbase; offsets[N] = E.
__global__ __launch_bounds__(1024)
void subscan_kernel(const int* __restrict__ tail2, int* __restrict__ subbase,
                    int* __restrict__ offsets, int N) {
    const int tid = threadIdx.x, lane = tid & 63, wid = tid >> 6;
    int v = min(tail2[tid], CAP2);
    int s = v;
#pragma unroll
    for (int off = 1; off < 64; off <<= 1) {
        int t = __shfl_up(s, off, 64);
        if (lane >= off) s += t;
    }
    __shared__ int ws[16];
    if (lane == 63) ws[wid] = s;
    __syncthreads();
    if (wid == 0) {
        int w = (lane < 16) ? ws[lane] : 0;
#pragma unroll
        for (int off = 1; off < 16; off <<= 1) {
            int t = __shfl_up(w, off, 64);
            if (lane >= off) w += t;
        }
        if (lane < 16) ws[lane] = w;
    }
    __syncthreads();
    int excl = (wid ? ws[wid - 1] : 0) + s - v;
    subbase[tid] = excl;
    if (tid == 1023) offsets[N] = excl + v;
}

// ---------------------------------------------------------------------------
// Merged: blocks [0,NSUB) do the per-sub-slice LDS counting sort (CSR build);
// blocks [NSUB,...) do setup (node_init + comb fp32 + pack_w1 + pack_w2).
__global__ __launch_bounds__(256)
void sort_setup_kernel(const unsigned int* __restrict__ subL, const int* __restrict__ tail2,
                       const int* __restrict__ subbase, int* __restrict__ offsets,
                       int* __restrict__ bucket, int N,
                       const int* __restrict__ x, const int* __restrict__ z,
                       const float* __restrict__ atom_emb, const float* __restrict__ z_emb,
                       unsigned short* __restrict__ hb, int nbNode,
                       const float* __restrict__ bond_emb, float* __restrict__ comb,
                       const float* __restrict__ W1, unsigned short* __restrict__ w1p,
                       const float* __restrict__ W2, unsigned short* __restrict__ w2p) {
    __shared__ int cnt[128], loff[128], wsum[4];
    __shared__ unsigned int sorted[CAP2];
    const int tid = threadIdx.x;
    if (blockIdx.x < NSUB) {
        // ---- csr_sort ----
        const int k = blockIdx.x;
        const int lane = tid & 63, wid = tid >> 6;
        const int len = min(tail2[k], CAP2);
        const int base = subbase[k];
        const int lo = (int)(((long long)k * N + 1023) >> 10);
        const int hi = (int)(((long long)(k + 1) * N + 1023) >> 10);
        const int nn = hi - lo;  // <= 128
        const unsigned int* src = subL + (size_t)k * CAP2;

        if (tid < 128) cnt[tid] = 0;
        __syncthreads();
        for (int i = tid; i < len; i += 256) atomicAdd(&cnt[src[i] >> 25], 1);
        __syncthreads();
        int v = (tid < 128) ? cnt[tid] : 0;
        int s = v;
#pragma unroll
        for (int off = 1; off < 64; off <<= 1) {
            int t = __shfl_up(s, off, 64);
            if (lane >= off) s += t;
        }
        if (lane == 63) wsum[wid] = s;
        __syncthreads();
        if (tid < 128) loff[tid] = ((wid == 1) ? wsum[0] : 0) + s - v;
        __syncthreads();
        if (tid < nn) offsets[lo + tid] = base + loff[tid];
        if (tid < 128) cnt[tid] = 0;
        __syncthreads();
        for (int i = tid; i < len; i += 256) {
            unsigned int e = src[i];
            int ld = e >> 25;
            int pos = loff[ld] + atomicAdd(&cnt[ld], 1);
            sorted[pos] = e & 0x1FFFFFFu;
        }
        __syncthreads();
        for (int i = tid; i < len; i += 256) bucket[base + i] = (int)sorted[i];
        return;
    }
    const int b = blockIdx.x - NSUB;
    if (b < nbNode) {
        // ---- node_init: hb0 = bf16( sum_f atom_emb[f,x[n,f],:] + z_emb[z[n],:] )
        int gid = b * 256 + tid;
        int node = gid >> 5;
        if (node >= N) return;
        int d0 = (gid & 31) * 4;
        float4 acc = *(const float4*)(z_emb + (size_t)z[node] * D + d0);
#pragma unroll
        for (int f = 0; f < 9; ++f) {
            int v = x[node * 9 + f];
            const float4 t = *(const float4*)(atom_emb + (size_t)(f * 119 + v) * D + d0);
            acc.x += t.x; acc.y += t.y; acc.z += t.z; acc.w += t.w;
        }
        ushort4 o;
        o.x = f2bf(acc.x); o.y = f2bf(acc.y); o.z = f2bf(acc.z); o.w = f2bf(acc.w);
        *(ushort4*)(hb + (size_t)node * D + d0) = o;
    } else if (b < nbNode + 216) {
        // ---- comb[layer][c][d] = b0[a0][d]+b1[a1][d]+b2[a2][d]  (fp32, L2-resident)
        int t = (b - nbNode) * 256 + tid;
        int layer = t / (216 * D);
        int idx = t - layer * (216 * D);
        int c = idx >> 7, d = idx & 127;
        int a0 = c / 36, a1 = (c / 6) % 6, a2 = c % 6;
        const float* bb = bond_emb + (size_t)layer * 3 * 6 * D;
        float v = bb[(0 * 6 + a0) * D + d] + bb[(1 * 6 + a1) * D + d] + bb[(2 * 6 + a2) * D + d];
        comb[(size_t)layer * 216 * D + idx] = v;
    } else {
        // ---- pack W [K][NCOLS] fp32 row-major -> fragment-linear bf16
        int isW2 = (b >= nbNode + 216 + 256);
        int t = (b - nbNode - 216 - (isW2 ? 256 : 0)) * 256 + tid;
        int layer = t >> 15;           // total = 32768 per layer for both
        int idx = t & 32767;
        int logN = isW2 ? 7 : 8;
        int NCOLS = 1 << logN;
        int k = idx >> logN, n = idx & (NCOLS - 1);
        int k0 = k >> 5, kq = k & 31, q = kq >> 3, j = kq & 7;
        int tt = n >> 4, ln = n & 15;
        size_t dest = (((size_t)k0 * (NCOLS >> 4) + tt) << 9) + ((q << 4) + ln) * 8 + j;
        const float* W = (isW2 ? W2 : W1) + (size_t)layer * 32768;
        unsigned short* Wp = (isW2 ? w2p : w1p) + (size_t)layer * 32768;
        Wp[dest] = f2bf(W[idx]);
    }
}

// ---------------------------------------------------------------------------
// pre[n] = bf16( (1+eps)*h[n] + sum_{e in in(n)} relu(h[src_e] + comb[c_e]) )
// 16 threads/node, 4-edge unroll. GT=1: h rows are RAW gemm2 output; apply
// relu(x*sc+sh) at load (fuses layer-0 bn_apply; sc/sh in 16 regs).
template <int GT>
__global__ __launch_bounds__(256)
void gather_reduce_kernel(const int* __restrict__ offsets, const int* __restrict__ bucket,
                          const float* __restrict__ comb,
                          const unsigned short* __restrict__ hb,
                          const float* __restrict__ sc2, const float* __restrict__ sh2,
                          const float* __restrict__ eps_l,
                          unsigned short* __restrict__ pre, int N) {
    int gid = blockIdx.x * blockDim.x + threadIdx.x;
    int node = gid >> 4;
    if (node >= N) return;
    int d0 = (gid & 15) * 8;

    float scv[8], shv[8];
    if constexpr (GT) {
        *(float4*)&scv[0] = *(const float4*)(sc2 + d0);
        *(float4*)&scv[4] = *(const float4*)(sc2 + d0 + 4);
        *(float4*)&shv[0] = *(const float4*)(sh2 + d0);
        *(float4*)&shv[4] = *(const float4*)(sh2 + d0 + 4);
    }
    auto tf = [&](unsigned short u, int j) -> float {
        float xv = bf2f(u);
        if constexpr (GT) xv = fmaxf(xv * scv[j] + shv[j], 0.f);
        return xv;
    };

    union U8 { int4 i; unsigned short u[8]; };
    union C8 { float4 v[2]; float f[8]; };
    float s = 1.0f + eps_l[0];
    float a[8];
    {
        U8 hv; hv.i = *(const int4*)(hb + (size_t)node * D + d0);
#pragma unroll
        for (int j = 0; j < 8; ++j) a[j] = tf(hv.u[j], j) * s;
    }
    const int beg = offsets[node], end = offsets[node + 1];
    for (int p = beg; p < end; p += 4) {
        int rem = end - p;
        int pk0 = bucket[p];
        int pk1 = bucket[rem > 1 ? p + 1 : p];
        int pk2 = bucket[rem > 2 ? p + 2 : p];
        int pk3 = bucket[rem > 3 ? p + 3 : p];
        U8 h0, h1, h2, h3;
        C8 c0, c1, c2, c3;
        h0.i = *(const int4*)(hb + (size_t)(pk0 & 0x1FFFF) * D + d0);
        c0.v[0] = *(const float4*)(comb + (size_t)(pk0 >> 17) * D + d0);
        c0.v[1] = *(const float4*)(comb + (size_t)(pk0 >> 17) * D + d0 + 4);
        h1.i = *(const int4*)(hb + (size_t)(pk1 & 0x1FFFF) * D + d0);
        c1.v[0] = *(const float4*)(comb + (size_t)(pk1 >> 17) * D + d0);
        c1.v[1] = *(const float4*)(comb + (size_t)(pk1 >> 17) * D + d0 + 4);
        h2.i = *(const int4*)(hb + (size_t)(pk2 & 0x1FFFF) * D + d0);
        c2.v[0] = *(const float4*)(comb + (size_t)(pk2 >> 17) * D + d0);
        c2.v[1] = *(const float4*)(comb + (size_t)(pk2 >> 17) * D + d0 + 4);
        h3.i = *(const int4*)(hb + (size_t)(pk3 & 0x1FFFF) * D + d0);
        c3.v[0] = *(const float4*)(comb + (size_t)(pk3 >> 17) * D + d0);
        c3.v[1] = *(const float4*)(comb + (size_t)(pk3 >> 17) * D + d0 + 4);
#pragma unroll
        for (int j = 0; j < 8; ++j) a[j] += fmaxf(tf(h0.u[j], j) + c0.f[j], 0.0f);
        if (rem > 1) {
#pragma unroll
            for (int j = 0; j < 8; ++j) a[j] += fmaxf(tf(h1.u[j], j) + c1.f[j], 0.0f);
        }
        if (rem > 2) {
#pragma unroll
            for (int j = 0; j < 8; ++j) a[j] += fmaxf(tf(h2.u[j], j) + c2.f[j], 0.0f);
        }
        if (rem > 3) {
#pragma unroll
            for (int j = 0; j < 8; ++j) a[j] += fmaxf(tf(h3.u[j], j) + c3.f[j], 0.0f);
        }
    }
    U8 o;
#pragma unroll
    for (int j = 0; j < 8; ++j) o.u[j] = f2bf(a[j]);
    *(int4*)(pre + (size_t)node * D + d0) = o.i;
}

// ---------------------------------------------------------------------------
// MFMA GEMM, B staged in LDS (2 x 32KB phases), A prefetched.
// TRANSFORM variant computes its own BN scale/shift in a prologue from the
// previous GEMM's gacc copies. Epilogue: LDS-staged coalesced C stores.
template <int K, int NCOLS, int TRANSFORM>
__global__ __launch_bounds__(256)
void mfma_gemm_kernel(const unsigned short* __restrict__ A,
                      const unsigned short* __restrict__ Wp,
                      const float* __restrict__ bias,
                      const float* __restrict__ gaccP,   // prev stats copies (TRANSFORM)
                      const float* __restrict__ gam, const float* __restrict__ bet,
                      float invN,
                      unsigned short* __restrict__ Cbf,
                      float* __restrict__ gacc, int M) {
    constexpr int NT = NCOLS / 16;
    constexpr int NCHUNK = K / 32;
    constexpr int CPP = NCHUNK / 2;
    constexpr int CTS = NCOLS + 8;  // padded ctile row stride
    constexpr int WS_SH = (64 * CTS > 16384) ? 64 * CTS : 16384;
    __shared__ unsigned short Ws[WS_SH];
    __shared__ float red[NCOLS * 2];
    __shared__ float tsc_s[TRANSFORM ? K : 1], tsh_s[TRANSFORM ? K : 1];

    const int tid = threadIdx.x;
    const int wave = tid >> 6, lane = tid & 63;
    const int quad = lane >> 4, ln = lane & 15;
    const int m_base = blockIdx.x * 64 + wave * 16;
    int arow = m_base + ln;
    if (arow >= M) arow = M - 1;
    const int kq = quad * 8;

    int4 araw[NCHUNK];
#pragma unroll
    for (int c = 0; c < NCHUNK; ++c)
        araw[c] = *(const int4*)(A + (size_t)arow * K + c * 32 + kq);

    for (int i = tid; i < NCOLS * 2; i += 256) red[i] = 0.f;

    if constexpr (TRANSFORM) {
        // prologue: reduce NCOPY gacc copies -> scale/shift for the K input cols
        for (int col = tid; col < K; col += 256) {
            float s = 0.f, q = 0.f;
            for (int c = 0; c < NCOPY; ++c) {
                const float* p = gaccP + (size_t)c * (K * 2);
                s += p[col];
                q += p[K + col];
            }
            float mean = s * invN;
            float var = q * invN - mean * mean;
            float inv = 1.0f / sqrtf(var + BN_EPS);
            float sc = gam[col] * inv;
            tsc_s[col] = sc;
            tsh_s[col] = bet[col] - mean * sc;
        }
    }

    floatx4 acc[NT];
#pragma unroll
    for (int t = 0; t < NT; ++t) acc[t] = (floatx4){0.f, 0.f, 0.f, 0.f};

#pragma unroll
    for (int ph = 0; ph < 2; ++ph) {
        if (ph) __syncthreads();
#pragma unroll
        for (int i = 0; i < 16384; i += 2048)
            *(int4*)&Ws[i + tid * 8] = *(const int4*)&Wp[ph * 16384 + i + tid * 8];
        __syncthreads();   // also covers tsc_s/tsh_s prologue writes (ph==0)
#pragma unroll
        for (int cc = 0; cc < CPP; ++cc) {
            const int c = ph * CPP + cc;
            short8 afrag;
            if constexpr (TRANSFORM) {
                union { int4 i; unsigned short u[8]; } raw;
                raw.i = araw[c];
                const int kb = c * 32 + kq;
                float4 sc0 = *(const float4*)&tsc_s[kb];
                float4 sc1 = *(const float4*)&tsc_s[kb + 4];
                float4 sh0 = *(const float4*)&tsh_s[kb];
                float4 sh1 = *(const float4*)&tsh_s[kb + 4];
                union { short8 v; unsigned short u[8]; } au;
                au.u[0] = f2bf(fmaxf(bf2f(raw.u[0]) * sc0.x + sh0.x, 0.f));
                au.u[1] = f2bf(fmaxf(bf2f(raw.u[1]) * sc0.y + sh0.y, 0.f));
                au.u[2] = f2bf(fmaxf(bf2f(raw.u[2]) * sc0.z + sh0.z, 0.f));
                au.u[3] = f2bf(fmaxf(bf2f(raw.u[3]) * sc0.w + sh0.w, 0.f));
                au.u[4] = f2bf(fmaxf(bf2f(raw.u[4]) * sc1.x + sh1.x, 0.f));
                au.u[5] = f2bf(fmaxf(bf2f(raw.u[5]) * sc1.y + sh1.y, 0.f));
                au.u[6] = f2bf(fmaxf(bf2f(raw.u[6]) * sc1.z + sh1.z, 0.f));
                au.u[7] = f2bf(fmaxf(bf2f(raw.u[7]) * sc1.w + sh1.w, 0.f));
                afrag = au.v;
            } else {
                afrag = __builtin_bit_cast(short8, araw[c]);
            }
#pragma unroll
            for (int t = 0; t < NT; ++t) {
                short8 bfrag = *(const short8*)&Ws[(((cc * NT) + t) << 9) + lane * 8];
                acc[t] = __builtin_amdgcn_mfma_f32_16x16x32_bf16(afrag, bfrag, acc[t], 0, 0, 0);
            }
        }
    }

    __syncthreads();  // all waves done reading Ws before reuse as ctile
#pragma unroll
    for (int t = 0; t < NT; ++t) {
        int col = t * 16 + ln;
        float bv = bias[col];
        float sv = 0.f, qv = 0.f;
#pragma unroll
        for (int r = 0; r < 4; ++r) {
            int lrow = wave * 16 + quad * 4 + r;
            float v = acc[t][r] + bv;
            Ws[lrow * CTS + col] = f2bf(v);
            if (m_base + quad * 4 + r < M) { sv += v; qv += v * v; }
        }
        sv += __shfl_xor(sv, 16, 64); sv += __shfl_xor(sv, 32, 64);
        qv += __shfl_xor(qv, 16, 64); qv += __shfl_xor(qv, 32, 64);
        if (quad == 0) {
            atomicAdd(&red[col], sv);
            atomicAdd(&red[NCOLS + col], qv);
        }
    }
    __syncthreads();
    // coalesced C write: contiguous 64*NCOLS shorts per block
    {
        constexpr int RI4 = NCOLS / 8;
        const int row0 = blockIdx.x * 64;
        unsigned short* cb = Cbf + (size_t)row0 * NCOLS;
        for (int i = tid; i < 64 * RI4; i += 256) {
            int row = i / RI4, cc = i - row * RI4;
            if (row0 + row < M)
                *(int4*)(cb + (size_t)i * 8) = *(const int4*)&Ws[row * CTS + cc * 8];
        }
    }
    float* gout = gacc + (size_t)(blockIdx.x & (NCOPY - 1)) * (NCOLS * 2);
    for (int i = tid; i < NCOLS * 2; i += 256) atomicAdd(&gout[i], red[i]);
}

// ---------------------------------------------------------------------------
// One tiny block: reduce NCOPY gacc copies -> scale/shift (for gather-l1 fuse).
template <int NCOLS>
__global__ void stats_final_kernel(const float* __restrict__ gacc,
                                   const float* __restrict__ g, const float* __restrict__ b,
                                   float* __restrict__ scale, float* __restrict__ shift,
                                   float invN) {
    int col = threadIdx.x;
    if (col < NCOLS) {
        float s = 0.f, q = 0.f;
        for (int c = 0; c < NCOPY; ++c) {
            const float* p = gacc + (size_t)c * (NCOLS * 2);
            s += p[col];
            q += p[NCOLS + col];
        }
        float mean = s * invN;
        float var = q * invN - mean * mean;
        float inv = 1.0f / sqrtf(var + BN_EPS);
        float sc = g[col] * inv;
        scale[col] = sc;
        shift[col] = b[col] - mean * sc;
    }
}

// ---------------------------------------------------------------------------
// Final BN apply (layer 1 only): self-computed scale/shift, h = bn(x) fp32.
__global__ __launch_bounds__(256)
void bn_apply_kernel(const unsigned short* __restrict__ Xb,
                     float* __restrict__ Yf,
                     const float* __restrict__ gacc,
                     const float* __restrict__ g, const float* __restrict__ b,
                     float invN, int N, int nblocks) {
    __shared__ float sc_s[D], sh_s[D];
    const int tid = threadIdx.x;
    if (tid < D) {
        float s = 0.f, q = 0.f;
        for (int c = 0; c < NCOPY; ++c) {
            const float* p = gacc + (size_t)c * (D * 2);
            s += p[tid];
            q += p[D + tid];
        }
        float mean = s * invN;
        float var = q * invN - mean * mean;
        float inv = 1.0f / sqrtf(var + BN_EPS);
        float sc = g[tid] * inv;
        sc_s[tid] = sc;
        sh_s[tid] = b[tid] - mean * sc;
    }
    __syncthreads();
    const int nchunk = (N + 7) / 8;  // 8 nodes per 256-thread chunk
    const int d0 = (tid & 31) * 4;
    for (int chunk = blockIdx.x; chunk < nchunk; chunk += nblocks) {
        int node = chunk * 8 + (tid >> 5);
        if (node >= N) continue;
        ushort4 xb = *(const ushort4*)(Xb + (size_t)node * D + d0);
        float4 v;
        v.x = bf2f(xb.x); v.y = bf2f(xb.y); v.z = bf2f(xb.z); v.w = bf2f(xb.w);
        float4 sc = *(const float4*)&sc_s[d0];
        float4 sh = *(const float4*)&sh_s[d0];
        float4 o;
        o.x = v.x * sc.x + sh.x;
        o.y = v.y * sc.y + sh.y;
        o.z = v.z * sc.z + sh.z;
        o.w = v.w * sc.w + sh.w;
        *(float4*)(Yf + (size_t)node * D + d0) = o;
    }
}

// ---------------------------------------------------------------------------
extern "C" void kernel_launch(void* const* d_in, const int* in_sizes, int n_in,
                              void* d_out, int out_size, void* d_ws, size_t ws_size,
                              hipStream_t stream) {
    const int*   x        = (const int*)d_in[0];
    const int*   z        = (const int*)d_in[1];
    const int*   ei       = (const int*)d_in[2];
    const int*   ea       = (const int*)d_in[3];
    const float* atom_emb = (const float*)d_in[4];
    const float* z_emb    = (const float*)d_in[5];
    const float* bond_emb = (const float*)d_in[6];
    const float* eps      = (const float*)d_in[7];
    const float* W1       = (const float*)d_in[8];
    const float* b1       = (const float*)d_in[9];
    const float* g1       = (const float*)d_in[10];
    const float* be1      = (const float*)d_in[11];
    const float* W2       = (const float*)d_in[12];
    const float* b2       = (const float*)d_in[13];
    const float* bng      = (const float*)d_in[14];
    const float* bnb      = (const float*)d_in[15];

    const int N = in_sizes[1];
    const int E = in_sizes[3] / 3;

    float* h = (float*)d_out;  // final [N,128] fp32

    const int ngb = (N + 63) / 64;   // GEMM grid
    const unsigned long long magic = ((1ULL << 44) / (unsigned int)N) + 1;  // exact for x < 2^27

    char* ws = (char*)d_ws;
    size_t off = 0;
    auto alloc = [&](size_t bytes) { void* p = ws + off; off += (bytes + 255) & ~(size_t)255; return p; };
    unsigned short* pre_bf  = (unsigned short*)alloc((size_t)N * D * 2);     // 25.6 MB
    unsigned short* out2_bf = (unsigned short*)alloc((size_t)N * D * 2);     // 25.6 MB (NOT aliased:
                                                                             //  gather-l1 reads it while writing pre)
    unsigned short* out1_bf = (unsigned short*)alloc((size_t)N * 2 * D * 2); // 51.2 MB
    unsigned short* hb      = (unsigned short*)alloc((size_t)N * D * 2);     // 25.6 MB
    int* offsets = (int*)alloc((size_t)(N + 1) * 4);
    int* bucket  = (int*)alloc((size_t)E * 4);
    unsigned int* subL = (unsigned int*)alloc((size_t)NSUB * CAP2 * 4); // 8 MB
    int* subbase = (int*)alloc(NSUB * 4);
    float* stats = (float*)alloc(256 * 4);   // scale2/shift2 for gather-l1 fuse
    // per-layer stats copies: 2x NCOPYx512 + 2x NCOPYx256, + tail2 (one memset)
    float* gstats = (float*)alloc(((size_t)NCOPY * 1536 + 1024) * 4);
    unsigned short* w1p  = (unsigned short*)alloc((size_t)2 * D * 2 * D * 2);
    unsigned short* w2p  = (unsigned short*)alloc((size_t)2 * 2 * D * D * 2);
    float* comb = (float*)alloc((size_t)2 * 216 * D * 4);    // fp32 comb, 221 KB

    float* scale2 = stats;          // 128
    float* shift2 = stats + 128;    // 128
    float* gacc1base = gstats;                            // [2][NCOPY*512]
    float* gacc2base = gstats + (size_t)2 * NCOPY * 512;  // [2][NCOPY*256]
    int* tail2 = (int*)(gstats + (size_t)NCOPY * 1536);   // 1024 ints

    const float invN = 1.0f / (float)N;
    const int ntiles = (E + 2047) / 2048;   // 2048-edge tiles, grid = ntiles
    const int nbNode = (N * 32 + 255) / 256;
    const int nbBN = (N + 63) / 64;   // bn_apply grid (8 chunks each)

    // --- CSR build + setup: partition -> subscan -> merged sort+setup ---
    hipMemsetAsync(gstats, 0, ((size_t)NCOPY * 1536 + 1024) * sizeof(float), stream);
    partition_kernel<<<ntiles, 256, 0, stream>>>(ei, ea, subL, tail2, E, N, magic);
    subscan_kernel<<<1, 1024, 0, stream>>>(tail2, subbase, offsets, N);
    sort_setup_kernel<<<NSUB + nbNode + 216 + 512, 256, 0, stream>>>(
        subL, tail2, subbase, offsets, bucket, N,
        x, z, atom_emb, z_emb, hb, nbNode, bond_emb, comb, W1, w1p, W2, w2p);

    for (int l = 0; l < 2; ++l) {
        float* gacc1 = gacc1base + (size_t)l * NCOPY * 512;
        float* gacc2 = gacc2base + (size_t)l * NCOPY * 256;

        if (l == 0) {
            gather_reduce_kernel<0><<<(N * 16 + 255) / 256, 256, 0, stream>>>(
                offsets, bucket, comb, hb, nullptr, nullptr, eps, pre_bf, N);
        } else {
            // fused: h = relu(bn(out2_l0)) applied at load (replaces bn_apply mode 0)
            gather_reduce_kernel<1><<<(N * 16 + 255) / 256, 256, 0, stream>>>(
                offsets, bucket, comb + (size_t)216 * D, out2_bf, scale2, shift2,
                eps + 1, pre_bf, N);
        }

        mfma_gemm_kernel<128, 256, 0><<<ngb, 256, 0, stream>>>(
            pre_bf, w1p + (size_t)l * D * 2 * D, b1 + (size_t)l * 2 * D,
            nullptr, nullptr, nullptr, invN, out1_bf, gacc1, N);

        mfma_gemm_kernel<256, 128, 1><<<ngb, 256, 0, stream>>>(
            out1_bf, w2p + (size_t)l * 2 * D * D, b2 + (size_t)l * D,
            gacc1, g1 + (size_t)l * 2 * D, be1 + (size_t)l * 2 * D, invN,
            out2_bf, gacc2, N);

        if (l == 0) {
            stats_final_kernel<128><<<1, 128, 0, stream>>>(
                gacc2, bng, bnb, scale2, shift2, invN);
        } else {
            bn_apply_kernel<<<nbBN, 256, 0, stream>>>(
                out2_bf, h, gacc2, bng + (size_t)l * D, bnb + (size_t)l * D,
                invN, N, nbBN);
        }
    }
}